// Round 2
// baseline (4652.479 us; speedup 1.0000x reference)
//
#include <hip/hip_runtime.h>
#include <hip/hip_bf16.h>
#include <stdint.h>
#include <stddef.h>

#define NEG_SLOPE 0.2f

__device__ __forceinline__ float bf2f(__hip_bfloat16 b){ return __bfloat162float(b); }

// ---------------------------------------------------------------- detectors
// flags[0]: 1 if edge_index is int64, 0 if int32.
// flags[1]: 1 if float tensors are fp32, 0 if bf16.
__global__ void detect_kernel(const unsigned* __restrict__ ei,
                              const unsigned* __restrict__ xw,
                              int* __restrict__ flags){
    if (blockIdx.x == 0 && threadIdx.x == 0){
        int is64 = 1;
        for (int i = 0; i < 64; i++)
            if (ei[2*i + 1] != 0u){ is64 = 0; break; }
        flags[0] = is64;
        // fp32 vs bf16: low 16 bits of each dword. bf16 data -> plausible bf16
        // (exponent in sane range or zero). fp32 data -> random mantissa bits.
        int plaus = 0;
        for (int i = 0; i < 256; i++){
            unsigned lo = xw[i] & 0xffffu;
            unsigned e  = (lo >> 7) & 0xffu;
            if ((lo & 0x7fffu) == 0u || (e >= 100u && e <= 140u)) plaus++;
        }
        flags[1] = (plaus < 128) ? 1 : 0;
    }
}

__global__ void convert_edges_kernel(const void* __restrict__ ei, const int* __restrict__ flags,
                                     int* __restrict__ srcs, int* __restrict__ dsts,
                                     int E, int Et){
    int i = blockIdx.x * 256 + threadIdx.x;
    if (i >= Et) return;
    if (i >= E){ srcs[i] = i - E; dsts[i] = i - E; return; }   // self loops
    if (flags[0]){
        const long long* p = (const long long*)ei;
        srcs[i] = (int)p[i];
        dsts[i] = (int)p[(size_t)E + i];
    } else {
        const int* p = (const int*)ei;
        srcs[i] = p[i];
        dsts[i] = p[(size_t)E + i];
    }
}

// ---------------------------------------------------------------- weights -> fp32
// Layout in wts block (floats):
//   W1: [0,16384)  W2: [16384,20480)  a1s: [20480,20608)  a1d: [20608,20736)
//   b1: [20736,20864)  a2s: [20864,20896)  a2d: [20896,20928)  b2: [20928,20960)
//   Wh: [20960,20992)  bh: [20992,20993)
#define WTS_TOTAL 20993
__global__ void prep_w_kernel(const void* W1, const void* W2, const void* a1s,
                              const void* a1d, const void* b1, const void* a2s,
                              const void* a2d, const void* b2, const void* Wh,
                              const void* bh, const int* __restrict__ flags,
                              float* __restrict__ w){
    int i = blockIdx.x * 256 + threadIdx.x;
    if (i >= WTS_TOTAL) return;
    const void* src; int off;
    if      (i < 16384){ src = W1;  off = i; }
    else if (i < 20480){ src = W2;  off = i - 16384; }
    else if (i < 20608){ src = a1s; off = i - 20480; }
    else if (i < 20736){ src = a1d; off = i - 20608; }
    else if (i < 20864){ src = b1;  off = i - 20736; }
    else if (i < 20896){ src = a2s; off = i - 20864; }
    else if (i < 20928){ src = a2d; off = i - 20896; }
    else if (i < 20960){ src = b2;  off = i - 20928; }
    else if (i < 20992){ src = Wh;  off = i - 20960; }
    else               { src = bh;  off = 0; }
    w[i] = flags[1] ? ((const float*)src)[off]
                    : bf2f(((const __hip_bfloat16*)src)[off]);
}

// ---------------------------------------------------------------- GEMM1
// h1[N,128] = x[N,128] @ W1[128,128], fp32 out. x dtype selected by flags[1].
__global__ __launch_bounds__(256) void gemm1_kernel(const void* __restrict__ xv,
                                                    const float* __restrict__ Wf,
                                                    const int* __restrict__ flags,
                                                    float* __restrict__ h1, int n){
    __shared__ float xs[32 * 128];                 // 16 KB
    __shared__ float ws[128 * 128];                // 64 KB
    const int t = threadIdx.x;
    const int row0 = blockIdx.x * 32;

    for (int i = t; i < 128 * 128; i += 256) ws[i] = Wf[i];

    if (flags[1]){                                  // fp32 x
        const float* xp = (const float*)xv + (size_t)row0 * 128;
        const int limit = (n - row0) * 128;
        for (int i = t; i < 32 * 128; i += 256)
            xs[i] = (i < limit) ? xp[i] : 0.f;
    } else {                                        // bf16 x
        const unsigned* xp = (const unsigned*)((const __hip_bfloat16*)xv + (size_t)row0 * 128);
        const int limit = (n - row0) * 64;
        for (int i = t; i < 32 * 128 / 2; i += 256){
            unsigned v = (i < limit) ? xp[i] : 0u;
            xs[2*i]     = __uint_as_float(v << 16);
            xs[2*i + 1] = __uint_as_float(v & 0xffff0000u);
        }
    }
    __syncthreads();

    const int col = t & 127;
    const int rg  = t >> 7;                        // 0..1 (16 rows each)
    float acc[16];
#pragma unroll
    for (int r = 0; r < 16; r++) acc[r] = 0.f;

    for (int k = 0; k < 128; k++){
        float w = ws[k*128 + col];
        const float* xr = &xs[(rg*16)*128 + k];
#pragma unroll
        for (int r = 0; r < 16; r++) acc[r] += xr[r*128] * w;   // LDS broadcast
    }
#pragma unroll
    for (int r = 0; r < 16; r++){
        int row = row0 + rg*16 + r;
        if (row < n) h1[(size_t)row*128 + col] = acc[r];
    }
}

// ---------------------------------------------------------------- attn logits L1
__global__ void attn1_kernel(const float* __restrict__ h1,
                             const float* __restrict__ a_s,
                             const float* __restrict__ a_d,
                             float* __restrict__ as1, float* __restrict__ ad1, int total){
    int i = blockIdx.x * 256 + threadIdx.x;        // i = node*8 + head
    if (i >= total) return;
    int node = i >> 3, h = i & 7;
    const float* hp = h1 + (size_t)node*128 + h*16;
    float s = 0.f, d = 0.f;
#pragma unroll
    for (int c = 0; c < 16; c++){
        float hv = hp[c];
        s += hv * a_s[h*16 + c];
        d += hv * a_d[h*16 + c];
    }
    as1[i] = s; ad1[i] = d;
}

// ---------------------------------------------------------------- softmax denom L1
__global__ void edgeA1_kernel(const int* __restrict__ srcs, const int* __restrict__ dsts,
                              const float* __restrict__ as1, const float* __restrict__ ad1,
                              float* __restrict__ s1, int Et){
    int e = blockIdx.x * 256 + threadIdx.x;
    if (e >= Et) return;
    int s = srcs[e], d = dsts[e];
    const float4* ap = (const float4*)(as1 + (size_t)s*8);
    const float4* bp = (const float4*)(ad1 + (size_t)d*8);
    float4 a0 = ap[0], a1 = ap[1], b0 = bp[0], b1 = bp[1];
    float v[8] = {a0.x+b0.x, a0.y+b0.y, a0.z+b0.z, a0.w+b0.w,
                  a1.x+b1.x, a1.y+b1.y, a1.z+b1.z, a1.w+b1.w};
#pragma unroll
    for (int h = 0; h < 8; h++){
        float u = v[h];
        u = u > 0.f ? u : NEG_SLOPE * u;
        atomicAdd(&s1[(size_t)d*8 + h], __expf(u));
    }
}

// ---------------------------------------------------------------- aggregate L1
// 32 threads per edge, 4 channels each (one float4).
__global__ void edgeB1_kernel(const int* __restrict__ srcs, const int* __restrict__ dsts,
                              const float* __restrict__ as1, const float* __restrict__ ad1,
                              const float* __restrict__ s1, const float* __restrict__ h1,
                              float* __restrict__ out1, int Et){
    int gid = blockIdx.x * 256 + threadIdx.x;
    int e = gid >> 5;
    if (e >= Et) return;
    int t  = gid & 31;
    int c0 = t * 4;
    int h  = t >> 2;                               // head = c0/16
    int s = srcs[e], d = dsts[e];
    float u = as1[(size_t)s*8 + h] + ad1[(size_t)d*8 + h];
    u = u > 0.f ? u : NEG_SLOPE * u;
    float w = __expf(u) / (s1[(size_t)d*8 + h] + 1e-16f);
    float4 hv = *(const float4*)(h1 + (size_t)s*128 + c0);
    float* op = out1 + (size_t)d*128 + c0;
    atomicAdd(op + 0, w * hv.x);
    atomicAdd(op + 1, w * hv.y);
    atomicAdd(op + 2, w * hv.z);
    atomicAdd(op + 3, w * hv.w);
}

// ---------------------------------------------------------------- bias + ELU L1
__global__ void act1_kernel(float* __restrict__ out1, const float* __restrict__ b1, int total){
    int i = blockIdx.x * 256 + threadIdx.x;
    if (i >= total) return;
    float v = out1[i] + b1[i & 127];
    out1[i] = v > 0.f ? v : expm1f(v);
}

// ---------------------------------------------------------------- GEMM2
// h2[N,32] = act1[N,128](f32) @ W2[128,32](f32)
__global__ __launch_bounds__(256) void gemm2_kernel(const float* __restrict__ act,
                                                    const float* __restrict__ W2,
                                                    float* __restrict__ h2, int n){
    __shared__ float ws[128 * 32];                 // 16 KB
    const int t = threadIdx.x;
    for (int i = t; i < 128*32; i += 256) ws[i] = W2[i];
    __syncthreads();
    int row = blockIdx.x * 8 + (t >> 5);
    int col = t & 31;
    if (row >= n) return;
    const float* ar = act + (size_t)row * 128;
    float acc = 0.f;
    for (int k = 0; k < 128; k++) acc += ar[k] * ws[k*32 + col];
    h2[(size_t)row*32 + col] = acc;
}

// ---------------------------------------------------------------- attn logits L2
__global__ void attn2_kernel(const float* __restrict__ h2,
                             const float* __restrict__ a_s,
                             const float* __restrict__ a_d,
                             float* __restrict__ as2, float* __restrict__ ad2, int n){
    int i = blockIdx.x * 256 + threadIdx.x;
    if (i >= n) return;
    const float* hp = h2 + (size_t)i * 32;
    float s = 0.f, d = 0.f;
#pragma unroll
    for (int c = 0; c < 32; c++){
        float hv = hp[c];
        s += hv * a_s[c];
        d += hv * a_d[c];
    }
    as2[i] = s; ad2[i] = d;
}

// ---------------------------------------------------------------- softmax denom L2
__global__ void edgeA2_kernel(const int* __restrict__ srcs, const int* __restrict__ dsts,
                              const float* __restrict__ as2, const float* __restrict__ ad2,
                              float* __restrict__ s2, int Et){
    int e = blockIdx.x * 256 + threadIdx.x;
    if (e >= Et) return;
    int s = srcs[e], d = dsts[e];
    float u = as2[s] + ad2[d];
    u = u > 0.f ? u : NEG_SLOPE * u;
    atomicAdd(&s2[d], __expf(u));
}

// ---------------------------------------------------------------- aggregate L2
// 8 threads per edge, one float4 each.
__global__ void edgeB2_kernel(const int* __restrict__ srcs, const int* __restrict__ dsts,
                              const float* __restrict__ as2, const float* __restrict__ ad2,
                              const float* __restrict__ s2, const float* __restrict__ h2,
                              float* __restrict__ out2, int Et){
    int gid = blockIdx.x * 256 + threadIdx.x;
    int e = gid >> 3;
    if (e >= Et) return;
    int t  = gid & 7;
    int c0 = t * 4;
    int s = srcs[e], d = dsts[e];
    float u = as2[s] + ad2[d];
    u = u > 0.f ? u : NEG_SLOPE * u;
    float w = __expf(u) / (s2[d] + 1e-16f);
    float4 hv = *(const float4*)(h2 + (size_t)s*32 + c0);
    float* op = out2 + (size_t)d*32 + c0;
    atomicAdd(op + 0, w * hv.x);
    atomicAdd(op + 1, w * hv.y);
    atomicAdd(op + 2, w * hv.z);
    atomicAdd(op + 3, w * hv.w);
}

// ---------------------------------------------------------------- head
__global__ void final_kernel(const float* __restrict__ out2,
                             const float* __restrict__ b2,
                             const float* __restrict__ Wh,
                             const float* __restrict__ bh,
                             const int* __restrict__ flags,
                             void* __restrict__ out, int n){
    int i = blockIdx.x * 256 + threadIdx.x;
    if (i >= n) return;
    const float* op = out2 + (size_t)i * 32;
    float acc = 0.f;
#pragma unroll
    for (int c = 0; c < 32; c++){
        float v = op[c] + b2[c];
        v = v > 0.f ? v : expm1f(v);
        acc += v * Wh[c];
    }
    float r = acc + bh[0];
    if (flags[1]) ((float*)out)[i] = r;
    else          ((__hip_bfloat16*)out)[i] = __float2bfloat16(r);
}

extern "C" void kernel_launch(void* const* d_in, const int* in_sizes, int n_in,
                              void* d_out, int out_size, void* d_ws, size_t ws_size,
                              hipStream_t stream){
    const void* x   = d_in[0];
    const void* ei  = d_in[1];
    const void* W1  = d_in[2];
    const void* a1s = d_in[3];
    const void* a1d = d_in[4];
    const void* b1  = d_in[5];
    const void* W2  = d_in[6];
    const void* a2s = d_in[7];
    const void* a2d = d_in[8];
    const void* b2  = d_in[9];
    const void* Wh  = d_in[10];
    const void* bh  = d_in[11];

    const int Nn = in_sizes[0] / 128;     // 100000
    const int Ee = in_sizes[1] / 2;       // 1600000
    const int Et = Ee + Nn;               // 1700000

    char* ws = (char*)d_ws;
    auto al = [](size_t v){ return (v + 255) & ~(size_t)255; };
    size_t off = 0;
    int*   flags = (int*)(ws + off);  off = al(off + 16);
    float* wts   = (float*)(ws + off); off = al(off + (size_t)WTS_TOTAL * 4);
    int*   srcs  = (int*)(ws + off);  off = al(off + (size_t)Et * 4);
    int*   dsts  = (int*)(ws + off);  off = al(off + (size_t)Et * 4);
    size_t o_h1 = off;
    float* h1   = (float*)(ws + off); off = al(off + (size_t)Nn * 128 * 4);
    float* as1  = (float*)(ws + off); off = al(off + (size_t)Nn * 8 * 4);
    float* ad1  = (float*)(ws + off); off = al(off + (size_t)Nn * 8 * 4);
    float* s1   = (float*)(ws + off); off = al(off + (size_t)Nn * 8 * 4);
    float* out1 = (float*)(ws + off); off = al(off + (size_t)Nn * 128 * 4);
    // layer-2 buffers alias h1's region (h1 dead after edgeB1)
    size_t o2 = o_h1;
    float* h2   = (float*)(ws + o2);  o2 += (size_t)Nn * 32 * 4;
    float* as2  = (float*)(ws + o2);  o2 += (size_t)Nn * 4;
    float* ad2  = (float*)(ws + o2);  o2 += (size_t)Nn * 4;
    float* s2   = (float*)(ws + o2);  o2 += (size_t)Nn * 4;
    float* out2 = (float*)(ws + o2);  o2 += (size_t)Nn * 32 * 4;

    float* W1f  = wts;
    float* W2f  = wts + 16384;
    float* a1sf = wts + 20480;
    float* a1df = wts + 20608;
    float* b1f  = wts + 20736;
    float* a2sf = wts + 20864;
    float* a2df = wts + 20896;
    float* b2f  = wts + 20928;
    float* Whf  = wts + 20960;
    float* bhf  = wts + 20992;

    // detection + prep
    detect_kernel<<<1, 64, 0, stream>>>((const unsigned*)ei, (const unsigned*)x, flags);
    convert_edges_kernel<<<(Et + 255) / 256, 256, 0, stream>>>(ei, flags, srcs, dsts, Ee, Et);
    prep_w_kernel<<<(WTS_TOTAL + 255) / 256, 256, 0, stream>>>(W1, W2, a1s, a1d, b1, a2s,
                                                               a2d, b2, Wh, bh, flags, wts);

    // layer 1
    gemm1_kernel<<<(Nn + 31) / 32, 256, 0, stream>>>(x, W1f, flags, h1, Nn);
    attn1_kernel<<<(Nn * 8 + 255) / 256, 256, 0, stream>>>(h1, a1sf, a1df, as1, ad1, Nn * 8);
    hipMemsetAsync(s1, 0, (size_t)Nn * 8 * 4, stream);
    hipMemsetAsync(out1, 0, (size_t)Nn * 128 * 4, stream);
    edgeA1_kernel<<<(Et + 255) / 256, 256, 0, stream>>>(srcs, dsts, as1, ad1, s1, Et);
    {
        long long thr = (long long)Et * 32;
        edgeB1_kernel<<<(unsigned)((thr + 255) / 256), 256, 0, stream>>>(srcs, dsts, as1, ad1, s1, h1, out1, Et);
    }
    act1_kernel<<<(Nn * 128 + 255) / 256, 256, 0, stream>>>(out1, b1f, Nn * 128);

    // layer 2
    gemm2_kernel<<<(Nn + 7) / 8, 256, 0, stream>>>(out1, W2f, h2, Nn);
    attn2_kernel<<<(Nn + 255) / 256, 256, 0, stream>>>(h2, a2sf, a2df, as2, ad2, Nn);
    hipMemsetAsync(s2, 0, (size_t)Nn * 4, stream);
    hipMemsetAsync(out2, 0, (size_t)Nn * 32 * 4, stream);
    edgeA2_kernel<<<(Et + 255) / 256, 256, 0, stream>>>(srcs, dsts, as2, ad2, s2, Et);
    {
        long long thr = (long long)Et * 8;
        edgeB2_kernel<<<(unsigned)((thr + 255) / 256), 256, 0, stream>>>(srcs, dsts, as2, ad2, s2, h2, out2, Et);
    }
    final_kernel<<<(Nn + 255) / 256, 256, 0, stream>>>(out2, b2f, Whf, bhf, flags, d_out, Nn);
}

// Round 3
// 752.757 us; speedup vs baseline: 6.1806x; 6.1806x over previous
//
#include <hip/hip_runtime.h>
#include <hip/hip_bf16.h>
#include <stdint.h>
#include <stddef.h>

#define NEG_SLOPE 0.2f
#define CHUNK 1024

__device__ __forceinline__ float bf2f(__hip_bfloat16 b){ return __bfloat162float(b); }

// ---------------------------------------------------------------- detectors
// flags[0]: 1 if edge_index is int64, 0 if int32.
// flags[1]: 1 if float tensors are fp32, 0 if bf16.
__global__ void detect_kernel(const unsigned* __restrict__ ei,
                              const unsigned* __restrict__ xw,
                              int* __restrict__ flags){
    if (blockIdx.x == 0 && threadIdx.x == 0){
        int is64 = 1;
        for (int i = 0; i < 64; i++)
            if (ei[2*i + 1] != 0u){ is64 = 0; break; }
        flags[0] = is64;
        int plaus = 0;
        for (int i = 0; i < 256; i++){
            unsigned lo = xw[i] & 0xffffu;
            unsigned e  = (lo >> 7) & 0xffu;
            if ((lo & 0x7fffu) == 0u || (e >= 100u && e <= 140u)) plaus++;
        }
        flags[1] = (plaus < 128) ? 1 : 0;
    }
}

// ---------------------------------------------------------------- weights -> fp32
#define WTS_TOTAL 20993
__global__ void prep_w_kernel(const void* W1, const void* W2, const void* a1s,
                              const void* a1d, const void* b1, const void* a2s,
                              const void* a2d, const void* b2, const void* Wh,
                              const void* bh, const int* __restrict__ flags,
                              float* __restrict__ w){
    int i = blockIdx.x * 256 + threadIdx.x;
    if (i >= WTS_TOTAL) return;
    const void* src; int off;
    if      (i < 16384){ src = W1;  off = i; }
    else if (i < 20480){ src = W2;  off = i - 16384; }
    else if (i < 20608){ src = a1s; off = i - 20480; }
    else if (i < 20736){ src = a1d; off = i - 20608; }
    else if (i < 20864){ src = b1;  off = i - 20736; }
    else if (i < 20896){ src = a2s; off = i - 20864; }
    else if (i < 20928){ src = a2d; off = i - 20896; }
    else if (i < 20960){ src = b2;  off = i - 20928; }
    else if (i < 20992){ src = Wh;  off = i - 20960; }
    else               { src = bh;  off = 0; }
    w[i] = flags[1] ? ((const float*)src)[off]
                    : bf2f(((const __hip_bfloat16*)src)[off]);
}

// ---------------------------------------------------------------- CSR build
__global__ void deg_kernel(const void* __restrict__ ei, const int* __restrict__ flags,
                           int* __restrict__ deg, int E, int Et){
    int e = blockIdx.x * 256 + threadIdx.x;
    if (e >= Et) return;
    int d;
    if (e >= E) d = e - E;
    else if (flags[0]) d = (int)((const long long*)ei)[(size_t)E + e];
    else               d = ((const int*)ei)[(size_t)E + e];
    atomicAdd(&deg[d], 1);
}

__global__ void scanA_kernel(const int* __restrict__ deg, int* __restrict__ bsum, int n){
    __shared__ int ts[256];
    int b = blockIdx.x, t = threadIdx.x;
    int base = b * CHUNK + t * 4;
    int s = 0;
#pragma unroll
    for (int k = 0; k < 4; k++){ int i = base + k; if (i < n) s += deg[i]; }
    ts[t] = s; __syncthreads();
    for (int off = 128; off > 0; off >>= 1){
        if (t < off) ts[t] += ts[t + off];
        __syncthreads();
    }
    if (t == 0) bsum[b] = ts[0];
}

__global__ void scanB_kernel(const int* __restrict__ bsum, int* __restrict__ boff,
                             int* __restrict__ rowptr, int nb, int n){
    if (blockIdx.x == 0 && threadIdx.x == 0){
        int run = 0;
        for (int b = 0; b < nb; b++){ boff[b] = run; run += bsum[b]; }
        rowptr[n] = run;
    }
}

__global__ void scanC_kernel(const int* __restrict__ deg, const int* __restrict__ boff,
                             int* __restrict__ rowptr, int* __restrict__ cursor, int n){
    __shared__ int ts[256];
    int b = blockIdx.x, t = threadIdx.x;
    int base = b * CHUNK + t * 4;
    int v[4]; int s = 0;
#pragma unroll
    for (int k = 0; k < 4; k++){ int i = base + k; v[k] = (i < n) ? deg[i] : 0; s += v[k]; }
    ts[t] = s; __syncthreads();
    for (int off = 1; off < 256; off <<= 1){
        int x = (t >= off) ? ts[t - off] : 0;
        __syncthreads();
        ts[t] += x;
        __syncthreads();
    }
    int run = boff[b] + ts[t] - s;      // exclusive prefix
#pragma unroll
    for (int k = 0; k < 4; k++){
        int i = base + k;
        if (i < n){ rowptr[i] = run; cursor[i] = run; }
        run += v[k];
    }
}

__global__ void fill_kernel(const void* __restrict__ ei, const int* __restrict__ flags,
                            int* __restrict__ cursor, int* __restrict__ csr_src,
                            int E, int Et){
    int e = blockIdx.x * 256 + threadIdx.x;
    if (e >= Et) return;
    int s, d;
    if (e >= E){ s = e - E; d = s; }
    else if (flags[0]){
        const long long* p = (const long long*)ei;
        s = (int)p[e]; d = (int)p[(size_t)E + e];
    } else {
        const int* p = (const int*)ei;
        s = p[e]; d = p[(size_t)E + e];
    }
    int pos = atomicAdd(&cursor[d], 1);
    csr_src[pos] = s;
}

// ---------------------------------------------------------------- GEMM1
__global__ __launch_bounds__(256) void gemm1_kernel(const void* __restrict__ xv,
                                                    const float* __restrict__ Wf,
                                                    const int* __restrict__ flags,
                                                    float* __restrict__ h1, int n){
    __shared__ float xs[32 * 128];                 // 16 KB
    __shared__ float ws[128 * 128];                // 64 KB
    const int t = threadIdx.x;
    const int row0 = blockIdx.x * 32;

    for (int i = t; i < 128 * 128; i += 256) ws[i] = Wf[i];

    if (flags[1]){                                  // fp32 x
        const float* xp = (const float*)xv + (size_t)row0 * 128;
        const int limit = (n - row0) * 128;
        for (int i = t; i < 32 * 128; i += 256)
            xs[i] = (i < limit) ? xp[i] : 0.f;
    } else {                                        // bf16 x
        const unsigned* xp = (const unsigned*)((const __hip_bfloat16*)xv + (size_t)row0 * 128);
        const int limit = (n - row0) * 64;
        for (int i = t; i < 32 * 128 / 2; i += 256){
            unsigned v = (i < limit) ? xp[i] : 0u;
            xs[2*i]     = __uint_as_float(v << 16);
            xs[2*i + 1] = __uint_as_float(v & 0xffff0000u);
        }
    }
    __syncthreads();

    const int col = t & 127;
    const int rg  = t >> 7;
    float acc[16];
#pragma unroll
    for (int r = 0; r < 16; r++) acc[r] = 0.f;

    for (int k = 0; k < 128; k++){
        float w = ws[k*128 + col];
        const float* xr = &xs[(rg*16)*128 + k];
#pragma unroll
        for (int r = 0; r < 16; r++) acc[r] += xr[r*128] * w;
    }
#pragma unroll
    for (int r = 0; r < 16; r++){
        int row = row0 + rg*16 + r;
        if (row < n) h1[(size_t)row*128 + col] = acc[r];
    }
}

// ---------------------------------------------------------------- attn logits L1
__global__ void attn1_kernel(const float* __restrict__ h1,
                             const float* __restrict__ a_s,
                             const float* __restrict__ a_d,
                             float* __restrict__ as1, float* __restrict__ ad1, int total){
    int i = blockIdx.x * 256 + threadIdx.x;        // i = node*8 + head
    if (i >= total) return;
    int node = i >> 3, h = i & 7;
    const float* hp = h1 + (size_t)node*128 + h*16;
    float s = 0.f, d = 0.f;
#pragma unroll
    for (int c = 0; c < 16; c++){
        float hv = hp[c];
        s += hv * a_s[h*16 + c];
        d += hv * a_d[h*16 + c];
    }
    as1[i] = s; ad1[i] = d;
}

// ---------------------------------------------------------------- gather L1 (+bias+ELU)
// One wave per dst node. Lane covers channels 2*lane, 2*lane+1; head = lane/8.
__global__ __launch_bounds__(256) void gather1_kernel(const int* __restrict__ rowptr,
                                                      const int* __restrict__ csr_src,
                                                      const float* __restrict__ as1,
                                                      const float* __restrict__ ad1,
                                                      const float* __restrict__ h1,
                                                      const float* __restrict__ b1,
                                                      float* __restrict__ out1, int n){
    int wid = blockIdx.x * 4 + (threadIdx.x >> 6);
    if (wid >= n) return;
    int lane = threadIdx.x & 63;
    int ch0  = lane * 2;
    int h    = lane >> 3;
    int start = rowptr[wid], end = rowptr[wid + 1];
    float adv = ad1[(size_t)wid * 8 + h];
    float den = 0.f, num0 = 0.f, num1 = 0.f;
    int src_next = (start < end) ? csr_src[start] : 0;
    for (int j = start; j < end; j++){
        int src = src_next;
        if (j + 1 < end) src_next = csr_src[j + 1];
        float u = as1[(size_t)src * 8 + h] + adv;
        u = u > 0.f ? u : NEG_SLOPE * u;
        float w = __expf(u);
        den += w;
        float2 hv = *(const float2*)(h1 + (size_t)src * 128 + ch0);
        num0 += w * hv.x;
        num1 += w * hv.y;
    }
    float inv = 1.f / (den + 1e-16f);
    float r0 = num0 * inv + b1[ch0];
    float r1 = num1 * inv + b1[ch0 + 1];
    r0 = r0 > 0.f ? r0 : expm1f(r0);
    r1 = r1 > 0.f ? r1 : expm1f(r1);
    *(float2*)(out1 + (size_t)wid * 128 + ch0) = make_float2(r0, r1);
}

// ---------------------------------------------------------------- GEMM2
__global__ __launch_bounds__(256) void gemm2_kernel(const float* __restrict__ act,
                                                    const float* __restrict__ W2,
                                                    float* __restrict__ h2, int n){
    __shared__ float ws[128 * 32];                 // 16 KB
    const int t = threadIdx.x;
    for (int i = t; i < 128*32; i += 256) ws[i] = W2[i];
    __syncthreads();
    int row = blockIdx.x * 8 + (t >> 5);
    int col = t & 31;
    if (row >= n) return;
    const float* ar = act + (size_t)row * 128;
    float acc = 0.f;
    for (int k = 0; k < 128; k++) acc += ar[k] * ws[k*32 + col];
    h2[(size_t)row*32 + col] = acc;
}

// ---------------------------------------------------------------- attn logits L2
__global__ void attn2_kernel(const float* __restrict__ h2,
                             const float* __restrict__ a_s,
                             const float* __restrict__ a_d,
                             float* __restrict__ as2, float* __restrict__ ad2, int n){
    int i = blockIdx.x * 256 + threadIdx.x;
    if (i >= n) return;
    const float* hp = h2 + (size_t)i * 32;
    float s = 0.f, d = 0.f;
#pragma unroll
    for (int c = 0; c < 32; c++){
        float hv = hp[c];
        s += hv * a_s[c];
        d += hv * a_d[c];
    }
    as2[i] = s; ad2[i] = d;
}

// ---------------------------------------------------------------- gather L2 + head (fused)
// One wave per dst node. half = lane/32 processes edges start+half, step 2;
// ch = lane&31. After loop, xor-32 combine, then fused b2+ELU+Wh dot + bh.
__global__ __launch_bounds__(256) void gather2_kernel(const int* __restrict__ rowptr,
                                                      const int* __restrict__ csr_src,
                                                      const float* __restrict__ as2,
                                                      const float* __restrict__ ad2,
                                                      const float* __restrict__ h2,
                                                      const float* __restrict__ b2,
                                                      const float* __restrict__ Wh,
                                                      const float* __restrict__ bh,
                                                      const int* __restrict__ flags,
                                                      void* __restrict__ out, int n){
    int wid = blockIdx.x * 4 + (threadIdx.x >> 6);
    if (wid >= n) return;
    int lane = threadIdx.x & 63;
    int half = lane >> 5;
    int ch   = lane & 31;
    int start = rowptr[wid], end = rowptr[wid + 1];
    float adv = ad2[wid];
    float den = 0.f, num = 0.f;
    for (int j = start + half; j < end; j += 2){
        int src = csr_src[j];
        float u = as2[src] + adv;
        u = u > 0.f ? u : NEG_SLOPE * u;
        float w = __expf(u);
        den += w;
        num += w * h2[(size_t)src * 32 + ch];
    }
    den += __shfl_xor(den, 32);
    num += __shfl_xor(num, 32);
    float v = num / (den + 1e-16f) + b2[ch];
    v = v > 0.f ? v : expm1f(v);
    float p = v * Wh[ch];
#pragma unroll
    for (int off = 16; off > 0; off >>= 1) p += __shfl_xor(p, off);
    if (lane == 0){
        float r = p + bh[0];
        if (flags[1]) ((float*)out)[wid] = r;
        else          ((__hip_bfloat16*)out)[wid] = __float2bfloat16(r);
    }
}

extern "C" void kernel_launch(void* const* d_in, const int* in_sizes, int n_in,
                              void* d_out, int out_size, void* d_ws, size_t ws_size,
                              hipStream_t stream){
    const void* x   = d_in[0];
    const void* ei  = d_in[1];

    const int Nn = in_sizes[0] / 128;     // 100000
    const int Ee = in_sizes[1] / 2;       // 1600000
    const int Et = Ee + Nn;               // 1700000
    const int nb = (Nn + CHUNK - 1) / CHUNK;

    char* ws = (char*)d_ws;
    auto al = [](size_t v){ return (v + 255) & ~(size_t)255; };
    size_t off = 0;
    int*   flags  = (int*)(ws + off);   off = al(off + 16);
    float* wts    = (float*)(ws + off); off = al(off + (size_t)WTS_TOTAL * 4);
    int*   deg    = (int*)(ws + off);   off = al(off + (size_t)Nn * 4);
    int*   bsum   = (int*)(ws + off);   off = al(off + (size_t)nb * 4);
    int*   boff   = (int*)(ws + off);   off = al(off + (size_t)nb * 4);
    int*   rowptr = (int*)(ws + off);   off = al(off + (size_t)(Nn + 1) * 4);
    int*   cursor = (int*)(ws + off);   off = al(off + (size_t)Nn * 4);
    int*   csrs   = (int*)(ws + off);   off = al(off + (size_t)Et * 4);
    size_t o_h1 = off;
    float* h1   = (float*)(ws + off); off = al(off + (size_t)Nn * 128 * 4);
    float* as1  = (float*)(ws + off); off = al(off + (size_t)Nn * 8 * 4);
    float* ad1  = (float*)(ws + off); off = al(off + (size_t)Nn * 8 * 4);
    float* out1 = (float*)(ws + off); off = al(off + (size_t)Nn * 128 * 4);
    // layer-2 buffers alias h1's region (h1 dead after gather1)
    size_t o2 = o_h1;
    float* h2   = (float*)(ws + o2);  o2 += (size_t)Nn * 32 * 4;
    float* as2  = (float*)(ws + o2);  o2 += (size_t)Nn * 4;
    float* ad2  = (float*)(ws + o2);  o2 += (size_t)Nn * 4;

    float* W1f  = wts;
    float* W2f  = wts + 16384;
    float* a1sf = wts + 20480;
    float* a1df = wts + 20608;
    float* b1f  = wts + 20736;
    float* a2sf = wts + 20864;
    float* a2df = wts + 20896;
    float* b2f  = wts + 20928;
    float* Whf  = wts + 20960;
    float* bhf  = wts + 20992;

    // detection + weight prep
    detect_kernel<<<1, 64, 0, stream>>>((const unsigned*)ei, (const unsigned*)x, flags);
    prep_w_kernel<<<(WTS_TOTAL + 255) / 256, 256, 0, stream>>>(d_in[2], d_in[6], d_in[3],
        d_in[4], d_in[5], d_in[7], d_in[8], d_in[9], d_in[10], d_in[11], flags, wts);

    // CSR build (dst-bucketed, shared by both layers)
    hipMemsetAsync(deg, 0, (size_t)Nn * 4, stream);
    deg_kernel<<<(Et + 255) / 256, 256, 0, stream>>>(ei, flags, deg, Ee, Et);
    scanA_kernel<<<nb, 256, 0, stream>>>(deg, bsum, Nn);
    scanB_kernel<<<1, 64, 0, stream>>>(bsum, boff, rowptr, nb, Nn);
    scanC_kernel<<<nb, 256, 0, stream>>>(deg, boff, rowptr, cursor, Nn);
    fill_kernel<<<(Et + 255) / 256, 256, 0, stream>>>(ei, flags, cursor, csrs, Ee, Et);

    // layer 1
    gemm1_kernel<<<(Nn + 31) / 32, 256, 0, stream>>>(x, W1f, flags, h1, Nn);
    attn1_kernel<<<(Nn * 8 + 255) / 256, 256, 0, stream>>>(h1, a1sf, a1df, as1, ad1, Nn * 8);
    gather1_kernel<<<(Nn + 3) / 4, 256, 0, stream>>>(rowptr, csrs, as1, ad1, h1, b1f, out1, Nn);

    // layer 2
    gemm2_kernel<<<(Nn + 7) / 8, 256, 0, stream>>>(out1, W2f, h2, Nn);
    attn2_kernel<<<(Nn + 255) / 256, 256, 0, stream>>>(h2, a2sf, a2df, as2, ad2, Nn);
    gather2_kernel<<<(Nn + 3) / 4, 256, 0, stream>>>(rowptr, csrs, as2, ad2, h2, b2f,
                                                     Whf, bhf, flags, d_out, Nn);
}

// Round 4
// 706.732 us; speedup vs baseline: 6.5831x; 1.0651x over previous
//
#include <hip/hip_runtime.h>
#include <hip/hip_bf16.h>
#include <stdint.h>
#include <stddef.h>

#define NEG_SLOPE 0.2f
#define CHUNK 1024

__device__ __forceinline__ float bf2f(__hip_bfloat16 b){ return __bfloat162float(b); }
__device__ __forceinline__ float lo_bf(unsigned u){ return __uint_as_float(u << 16); }
__device__ __forceinline__ float hi_bf(unsigned u){ return __uint_as_float(u & 0xffff0000u); }
__device__ __forceinline__ float lrelu(float u){ return fmaxf(u, NEG_SLOPE * u); }

// ---------------------------------------------------------------- detectors
// flags[0]: 1 if edge_index is int64, 0 if int32.
// flags[1]: 1 if float tensors are fp32, 0 if bf16.
__global__ void detect_kernel(const unsigned* __restrict__ ei,
                              const unsigned* __restrict__ xw,
                              int* __restrict__ flags){
    if (blockIdx.x == 0 && threadIdx.x == 0){
        int is64 = 1;
        for (int i = 0; i < 64; i++)
            if (ei[2*i + 1] != 0u){ is64 = 0; break; }
        flags[0] = is64;
        int plaus = 0;
        for (int i = 0; i < 256; i++){
            unsigned lo = xw[i] & 0xffffu;
            unsigned e  = (lo >> 7) & 0xffu;
            if ((lo & 0x7fffu) == 0u || (e >= 100u && e <= 140u)) plaus++;
        }
        flags[1] = (plaus < 128) ? 1 : 0;
    }
}

// ---------------------------------------------------------------- weights -> fp32
#define WTS_TOTAL 20993
__global__ void prep_w_kernel(const void* W1, const void* W2, const void* a1s,
                              const void* a1d, const void* b1, const void* a2s,
                              const void* a2d, const void* b2, const void* Wh,
                              const void* bh, const int* __restrict__ flags,
                              float* __restrict__ w){
    int i = blockIdx.x * 256 + threadIdx.x;
    if (i >= WTS_TOTAL) return;
    const void* src; int off;
    if      (i < 16384){ src = W1;  off = i; }
    else if (i < 20480){ src = W2;  off = i - 16384; }
    else if (i < 20608){ src = a1s; off = i - 20480; }
    else if (i < 20736){ src = a1d; off = i - 20608; }
    else if (i < 20864){ src = b1;  off = i - 20736; }
    else if (i < 20896){ src = a2s; off = i - 20864; }
    else if (i < 20928){ src = a2d; off = i - 20896; }
    else if (i < 20960){ src = b2;  off = i - 20928; }
    else if (i < 20992){ src = Wh;  off = i - 20960; }
    else               { src = bh;  off = 0; }
    w[i] = flags[1] ? ((const float*)src)[off]
                    : bf2f(((const __hip_bfloat16*)src)[off]);
}

// ---------------------------------------------------------------- CSR build
__global__ void deg_kernel(const void* __restrict__ ei, const int* __restrict__ flags,
                           int* __restrict__ deg, int E, int Et){
    int e = blockIdx.x * 256 + threadIdx.x;
    if (e >= Et) return;
    int d;
    if (e >= E) d = e - E;
    else if (flags[0]) d = (int)((const long long*)ei)[(size_t)E + e];
    else               d = ((const int*)ei)[(size_t)E + e];
    atomicAdd(&deg[d], 1);
}

__global__ void scanA_kernel(const int* __restrict__ deg, int* __restrict__ bsum, int n){
    __shared__ int ts[256];
    int b = blockIdx.x, t = threadIdx.x;
    int base = b * CHUNK + t * 4;
    int s = 0;
#pragma unroll
    for (int k = 0; k < 4; k++){ int i = base + k; if (i < n) s += deg[i]; }
    ts[t] = s; __syncthreads();
    for (int off = 128; off > 0; off >>= 1){
        if (t < off) ts[t] += ts[t + off];
        __syncthreads();
    }
    if (t == 0) bsum[b] = ts[0];
}

__global__ void scanB_kernel(const int* __restrict__ bsum, int* __restrict__ boff,
                             int* __restrict__ rowptr, int nb, int n){
    if (blockIdx.x == 0 && threadIdx.x == 0){
        int run = 0;
        for (int b = 0; b < nb; b++){ boff[b] = run; run += bsum[b]; }
        rowptr[n] = run;
    }
}

__global__ void scanC_kernel(const int* __restrict__ deg, const int* __restrict__ boff,
                             int* __restrict__ rowptr, int* __restrict__ cursor, int n){
    __shared__ int ts[256];
    int b = blockIdx.x, t = threadIdx.x;
    int base = b * CHUNK + t * 4;
    int v[4]; int s = 0;
#pragma unroll
    for (int k = 0; k < 4; k++){ int i = base + k; v[k] = (i < n) ? deg[i] : 0; s += v[k]; }
    ts[t] = s; __syncthreads();
    for (int off = 1; off < 256; off <<= 1){
        int x = (t >= off) ? ts[t - off] : 0;
        __syncthreads();
        ts[t] += x;
        __syncthreads();
    }
    int run = boff[b] + ts[t] - s;      // exclusive prefix
#pragma unroll
    for (int k = 0; k < 4; k++){
        int i = base + k;
        if (i < n){ rowptr[i] = run; cursor[i] = run; }
        run += v[k];
    }
}

__global__ void fill_kernel(const void* __restrict__ ei, const int* __restrict__ flags,
                            int* __restrict__ cursor, int* __restrict__ csr_src,
                            int E, int Et){
    int e = blockIdx.x * 256 + threadIdx.x;
    if (e >= Et) return;
    int s, d;
    if (e >= E){ s = e - E; d = s; }
    else if (flags[0]){
        const long long* p = (const long long*)ei;
        s = (int)p[e]; d = (int)p[(size_t)E + e];
    } else {
        const int* p = (const int*)ei;
        s = p[e]; d = p[(size_t)E + e];
    }
    int pos = atomicAdd(&cursor[d], 1);
    csr_src[pos] = s;
}

// ---------------------------------------------------------------- GEMM1 + attn1 fused
// h1b[N,128](bf16) = x @ W1; as1/ad1[N,8] from fp32 accumulators (exact logits).
__global__ __launch_bounds__(256) void gemm1_kernel(const void* __restrict__ xv,
                                                    const float* __restrict__ Wf,
                                                    const float* __restrict__ aS,
                                                    const float* __restrict__ aD,
                                                    const int* __restrict__ flags,
                                                    __hip_bfloat16* __restrict__ h1b,
                                                    float* __restrict__ as1,
                                                    float* __restrict__ ad1, int n){
    __shared__ float xs[32 * 128];                 // 16 KB
    __shared__ float ws[128 * 128];                // 64 KB
    const int t = threadIdx.x;
    const int row0 = blockIdx.x * 32;

    for (int i = t; i < 128 * 128; i += 256) ws[i] = Wf[i];

    if (flags[1]){                                  // fp32 x
        const float* xp = (const float*)xv + (size_t)row0 * 128;
        const int limit = (n - row0) * 128;
        for (int i = t; i < 32 * 128; i += 256)
            xs[i] = (i < limit) ? xp[i] : 0.f;
    } else {                                        // bf16 x
        const unsigned* xp = (const unsigned*)((const __hip_bfloat16*)xv + (size_t)row0 * 128);
        const int limit = (n - row0) * 64;
        for (int i = t; i < 32 * 128 / 2; i += 256){
            unsigned v = (i < limit) ? xp[i] : 0u;
            xs[2*i]     = __uint_as_float(v << 16);
            xs[2*i + 1] = __uint_as_float(v & 0xffff0000u);
        }
    }
    __syncthreads();

    const int col = t & 127;
    const int rg  = t >> 7;
    const int lane = t & 63;
    const int head = col >> 4;
    const float asv = aS[col];                     // a1_src[head][col&15]
    const float adv = aD[col];
    float acc[16];
#pragma unroll
    for (int r = 0; r < 16; r++) acc[r] = 0.f;

    for (int k = 0; k < 128; k++){
        float w = ws[k*128 + col];
        const float* xr = &xs[(rg*16)*128 + k];
#pragma unroll
        for (int r = 0; r < 16; r++) acc[r] += xr[r*128] * w;
    }
#pragma unroll
    for (int r = 0; r < 16; r++){
        int row = row0 + rg*16 + r;
        if (row < n){
            h1b[(size_t)row*128 + col] = __float2bfloat16(acc[r]);
            // 16-lane reduction for attn logits (exact, from fp32 acc)
            float vs = acc[r] * asv;
            float vd = acc[r] * adv;
#pragma unroll
            for (int off = 1; off < 16; off <<= 1){
                vs += __shfl_xor(vs, off);
                vd += __shfl_xor(vd, off);
            }
            if ((lane & 15) == 0){
                as1[(size_t)row*8 + head] = vs;
                ad1[(size_t)row*8 + head] = vd;
            }
        }
    }
}

// ---------------------------------------------------------------- gather L1 (+bias+ELU)
// One wave per dst node. Lane covers channels 2*lane, 2*lane+1 (bf16 pair); head = lane/8.
__global__ __launch_bounds__(256) void gather1_kernel(const int* __restrict__ rowptr,
                                                      const int* __restrict__ csr_src,
                                                      const float* __restrict__ as1,
                                                      const float* __restrict__ ad1,
                                                      const unsigned* __restrict__ h1u,
                                                      const float* __restrict__ b1,
                                                      float* __restrict__ out1, int n){
    int wid = blockIdx.x * 4 + (threadIdx.x >> 6);
    if (wid >= n) return;
    int lane = threadIdx.x & 63;
    int ch0  = lane * 2;
    int h    = lane >> 3;
    int start = rowptr[wid], end = rowptr[wid + 1];
    float adv = ad1[(size_t)wid * 8 + h];
    float den = 0.f, num0 = 0.f, num1 = 0.f;
    int src_next = (start < end) ? csr_src[start] : 0;
    for (int j = start; j < end; j++){
        int src = src_next;
        if (j + 1 < end) src_next = csr_src[j + 1];
        float u = lrelu(as1[(size_t)src * 8 + h] + adv);
        float w = __expf(u);
        unsigned hv = h1u[(size_t)src * 64 + lane];
        den += w;
        num0 += w * lo_bf(hv);
        num1 += w * hi_bf(hv);
    }
    float inv = 1.f / (den + 1e-16f);
    float r0 = num0 * inv + b1[ch0];
    float r1 = num1 * inv + b1[ch0 + 1];
    r0 = r0 > 0.f ? r0 : expm1f(r0);
    r1 = r1 > 0.f ? r1 : expm1f(r1);
    *(float2*)(out1 + (size_t)wid * 128 + ch0) = make_float2(r0, r1);
}

// ---------------------------------------------------------------- GEMM2 + attn2 fused
// h2b[N,32](bf16) = out1 @ W2; as2/ad2[N] from fp32 accumulators.
__global__ __launch_bounds__(256) void gemm2_kernel(const float* __restrict__ act,
                                                    const float* __restrict__ W2,
                                                    const float* __restrict__ aS,
                                                    const float* __restrict__ aD,
                                                    __hip_bfloat16* __restrict__ h2b,
                                                    float* __restrict__ as2,
                                                    float* __restrict__ ad2, int n){
    __shared__ float ws[128 * 32];                 // 16 KB
    const int t = threadIdx.x;
    for (int i = t; i < 128*32; i += 256) ws[i] = W2[i];
    __syncthreads();
    int row = blockIdx.x * 8 + (t >> 5);
    int col = t & 31;
    int lane = t & 63;
    if (row >= n) return;
    const float* ar = act + (size_t)row * 128;
    float acc = 0.f;
    for (int k = 0; k < 128; k++) acc += ar[k] * ws[k*32 + col];
    h2b[(size_t)row*32 + col] = __float2bfloat16(acc);
    float vs = acc * aS[col];
    float vd = acc * aD[col];
#pragma unroll
    for (int off = 1; off < 32; off <<= 1){
        vs += __shfl_xor(vs, off);
        vd += __shfl_xor(vd, off);
    }
    if ((lane & 31) == 0){
        as2[row] = vs;
        ad2[row] = vd;
    }
}

// ---------------------------------------------------------------- gather L2 + head (fused)
// One wave per dst node, 4 edges in flight (16 lanes each, 2 bf16 ch/lane).
__global__ __launch_bounds__(256) void gather2_kernel(const int* __restrict__ rowptr,
                                                      const int* __restrict__ csr_src,
                                                      const float* __restrict__ as2,
                                                      const float* __restrict__ ad2,
                                                      const unsigned* __restrict__ h2u,
                                                      const float* __restrict__ b2,
                                                      const float* __restrict__ Wh,
                                                      const float* __restrict__ bh,
                                                      const int* __restrict__ flags,
                                                      void* __restrict__ out, int n){
    int wid = blockIdx.x * 4 + (threadIdx.x >> 6);
    if (wid >= n) return;
    int lane = threadIdx.x & 63;
    int q    = lane >> 4;                           // which of 4 concurrent edges
    int i2   = lane & 15;                           // ch pair index
    int ch0  = i2 * 2;
    int start = rowptr[wid], end = rowptr[wid + 1];
    float adv = ad2[wid];
    float den = 0.f, num0 = 0.f, num1 = 0.f;
    for (int j = start + q; j < end; j += 4){
        int src = csr_src[j];
        float u = lrelu(as2[src] + adv);
        float w = __expf(u);
        unsigned hv = h2u[(size_t)src * 16 + i2];
        den += w;
        num0 += w * lo_bf(hv);
        num1 += w * hi_bf(hv);
    }
    den  += __shfl_xor(den, 16);  den  += __shfl_xor(den, 32);
    num0 += __shfl_xor(num0, 16); num0 += __shfl_xor(num0, 32);
    num1 += __shfl_xor(num1, 16); num1 += __shfl_xor(num1, 32);
    float inv = 1.f / (den + 1e-16f);
    float v0 = num0 * inv + b2[ch0];
    float v1 = num1 * inv + b2[ch0 + 1];
    v0 = v0 > 0.f ? v0 : expm1f(v0);
    v1 = v1 > 0.f ? v1 : expm1f(v1);
    float p = v0 * Wh[ch0] + v1 * Wh[ch0 + 1];
#pragma unroll
    for (int off = 1; off < 16; off <<= 1) p += __shfl_xor(p, off);
    if (lane == 0){
        float r = p + bh[0];
        if (flags[1]) ((float*)out)[wid] = r;
        else          ((__hip_bfloat16*)out)[wid] = __float2bfloat16(r);
    }
}

extern "C" void kernel_launch(void* const* d_in, const int* in_sizes, int n_in,
                              void* d_out, int out_size, void* d_ws, size_t ws_size,
                              hipStream_t stream){
    const void* x   = d_in[0];
    const void* ei  = d_in[1];

    const int Nn = in_sizes[0] / 128;     // 100000
    const int Ee = in_sizes[1] / 2;       // 1600000
    const int Et = Ee + Nn;               // 1700000
    const int nb = (Nn + CHUNK - 1) / CHUNK;

    char* ws = (char*)d_ws;
    auto al = [](size_t v){ return (v + 255) & ~(size_t)255; };
    size_t off = 0;
    int*   flags  = (int*)(ws + off);   off = al(off + 16);
    float* wts    = (float*)(ws + off); off = al(off + (size_t)WTS_TOTAL * 4);
    int*   deg    = (int*)(ws + off);   off = al(off + (size_t)Nn * 4);
    int*   bsum   = (int*)(ws + off);   off = al(off + (size_t)nb * 4);
    int*   boff   = (int*)(ws + off);   off = al(off + (size_t)nb * 4);
    int*   rowptr = (int*)(ws + off);   off = al(off + (size_t)(Nn + 1) * 4);
    int*   cursor = (int*)(ws + off);   off = al(off + (size_t)Nn * 4);
    int*   csrs   = (int*)(ws + off);   off = al(off + (size_t)Et * 4);
    size_t o_h1 = off;
    __hip_bfloat16* h1b = (__hip_bfloat16*)(ws + off); off = al(off + (size_t)Nn * 128 * 2);
    float* as1  = (float*)(ws + off); off = al(off + (size_t)Nn * 8 * 4);
    float* ad1  = (float*)(ws + off); off = al(off + (size_t)Nn * 8 * 4);
    float* out1 = (float*)(ws + off); off = al(off + (size_t)Nn * 128 * 4);
    // layer-2 buffers alias h1b region (dead after gather1)
    size_t o2 = o_h1;
    __hip_bfloat16* h2b = (__hip_bfloat16*)(ws + o2); o2 += (size_t)Nn * 32 * 2;
    float* as2  = (float*)(ws + o2);  o2 += (size_t)Nn * 4;
    float* ad2  = (float*)(ws + o2);  o2 += (size_t)Nn * 4;

    float* W1f  = wts;
    float* W2f  = wts + 16384;
    float* a1sf = wts + 20480;
    float* a1df = wts + 20608;
    float* b1f  = wts + 20736;
    float* a2sf = wts + 20864;
    float* a2df = wts + 20896;
    float* b2f  = wts + 20928;
    float* Whf  = wts + 20960;
    float* bhf  = wts + 20992;

    // detection + weight prep
    detect_kernel<<<1, 64, 0, stream>>>((const unsigned*)ei, (const unsigned*)x, flags);
    prep_w_kernel<<<(WTS_TOTAL + 255) / 256, 256, 0, stream>>>(d_in[2], d_in[6], d_in[3],
        d_in[4], d_in[5], d_in[7], d_in[8], d_in[9], d_in[10], d_in[11], flags, wts);

    // CSR build (dst-bucketed, shared by both layers)
    hipMemsetAsync(deg, 0, (size_t)Nn * 4, stream);
    deg_kernel<<<(Et + 255) / 256, 256, 0, stream>>>(ei, flags, deg, Ee, Et);
    scanA_kernel<<<nb, 256, 0, stream>>>(deg, bsum, Nn);
    scanB_kernel<<<1, 64, 0, stream>>>(bsum, boff, rowptr, nb, Nn);
    scanC_kernel<<<nb, 256, 0, stream>>>(deg, boff, rowptr, cursor, Nn);
    fill_kernel<<<(Et + 255) / 256, 256, 0, stream>>>(ei, flags, cursor, csrs, Ee, Et);

    // layer 1
    gemm1_kernel<<<(Nn + 31) / 32, 256, 0, stream>>>(x, W1f, a1sf, a1df, flags,
                                                     h1b, as1, ad1, Nn);
    gather1_kernel<<<(Nn + 3) / 4, 256, 0, stream>>>(rowptr, csrs, as1, ad1,
                                                     (const unsigned*)h1b, b1f, out1, Nn);

    // layer 2
    gemm2_kernel<<<(Nn + 7) / 8, 256, 0, stream>>>(out1, W2f, a2sf, a2df, h2b, as2, ad2, Nn);
    gather2_kernel<<<(Nn + 3) / 4, 256, 0, stream>>>(rowptr, csrs, as2, ad2,
                                                     (const unsigned*)h2b, b2f,
                                                     Whf, bhf, flags, d_out, Nn);
}

// Round 5
// 635.093 us; speedup vs baseline: 7.3257x; 1.1128x over previous
//
#include <hip/hip_runtime.h>
#include <hip/hip_bf16.h>
#include <stdint.h>
#include <stddef.h>

#define NEG_SLOPE 0.2f
#define CHUNK 1024
#define XS 136   // padded LDS row stride in bf16 elems (272 B, 16B-aligned, kills 256B bank alias)

typedef __bf16 bf16x8 __attribute__((ext_vector_type(8)));
typedef float  f32x4  __attribute__((ext_vector_type(4)));

__device__ __forceinline__ float bf2f(__hip_bfloat16 b){ return __bfloat162float(b); }
__device__ __forceinline__ float lo_bf(unsigned u){ return __uint_as_float(u << 16); }
__device__ __forceinline__ float hi_bf(unsigned u){ return __uint_as_float(u & 0xffff0000u); }
__device__ __forceinline__ float lrelu(float u){ return fmaxf(u, NEG_SLOPE * u); }

// ---------------------------------------------------------------- detectors
// flags[0]: 1 if edge_index is int64, 0 if int32.
// flags[1]: 1 if float tensors are fp32, 0 if bf16.
__global__ void detect_kernel(const unsigned* __restrict__ ei,
                              const unsigned* __restrict__ xw,
                              int* __restrict__ flags){
    if (blockIdx.x == 0 && threadIdx.x == 0){
        int is64 = 1;
        for (int i = 0; i < 64; i++)
            if (ei[2*i + 1] != 0u){ is64 = 0; break; }
        flags[0] = is64;
        int plaus = 0;
        for (int i = 0; i < 256; i++){
            unsigned lo = xw[i] & 0xffffu;
            unsigned e  = (lo >> 7) & 0xffu;
            if ((lo & 0x7fffu) == 0u || (e >= 100u && e <= 140u)) plaus++;
        }
        flags[1] = (plaus < 128) ? 1 : 0;
    }
}

// ---------------------------------------------------------------- weights -> fp32
#define WTS_TOTAL 20993
__global__ void prep_w_kernel(const void* W1, const void* W2, const void* a1s,
                              const void* a1d, const void* b1, const void* a2s,
                              const void* a2d, const void* b2, const void* Wh,
                              const void* bh, const int* __restrict__ flags,
                              float* __restrict__ w){
    int i = blockIdx.x * 256 + threadIdx.x;
    if (i >= WTS_TOTAL) return;
    const void* src; int off;
    if      (i < 16384){ src = W1;  off = i; }
    else if (i < 20480){ src = W2;  off = i - 16384; }
    else if (i < 20608){ src = a1s; off = i - 20480; }
    else if (i < 20736){ src = a1d; off = i - 20608; }
    else if (i < 20864){ src = b1;  off = i - 20736; }
    else if (i < 20896){ src = a2s; off = i - 20864; }
    else if (i < 20928){ src = a2d; off = i - 20896; }
    else if (i < 20960){ src = b2;  off = i - 20928; }
    else if (i < 20992){ src = Wh;  off = i - 20960; }
    else               { src = bh;  off = 0; }
    w[i] = flags[1] ? ((const float*)src)[off]
                    : bf2f(((const __hip_bfloat16*)src)[off]);
}

// ---------------------------------------------------------------- CSR build
__global__ void deg_kernel(const void* __restrict__ ei, const int* __restrict__ flags,
                           int* __restrict__ deg, int E, int Et){
    int e = blockIdx.x * 256 + threadIdx.x;
    if (e >= Et) return;
    int d;
    if (e >= E) d = e - E;
    else if (flags[0]) d = (int)((const long long*)ei)[(size_t)E + e];
    else               d = ((const int*)ei)[(size_t)E + e];
    atomicAdd(&deg[d], 1);
}

__global__ void scanA_kernel(const int* __restrict__ deg, int* __restrict__ bsum, int n){
    __shared__ int ts[256];
    int b = blockIdx.x, t = threadIdx.x;
    int base = b * CHUNK + t * 4;
    int s = 0;
#pragma unroll
    for (int k = 0; k < 4; k++){ int i = base + k; if (i < n) s += deg[i]; }
    ts[t] = s; __syncthreads();
    for (int off = 128; off > 0; off >>= 1){
        if (t < off) ts[t] += ts[t + off];
        __syncthreads();
    }
    if (t == 0) bsum[b] = ts[0];
}

__global__ void scanB_kernel(const int* __restrict__ bsum, int* __restrict__ boff,
                             int* __restrict__ rowptr, int nb, int n){
    if (blockIdx.x == 0 && threadIdx.x == 0){
        int run = 0;
        for (int b = 0; b < nb; b++){ boff[b] = run; run += bsum[b]; }
        rowptr[n] = run;
    }
}

__global__ void scanC_kernel(const int* __restrict__ deg, const int* __restrict__ boff,
                             int* __restrict__ rowptr, int* __restrict__ cursor, int n){
    __shared__ int ts[256];
    int b = blockIdx.x, t = threadIdx.x;
    int base = b * CHUNK + t * 4;
    int v[4]; int s = 0;
#pragma unroll
    for (int k = 0; k < 4; k++){ int i = base + k; v[k] = (i < n) ? deg[i] : 0; s += v[k]; }
    ts[t] = s; __syncthreads();
    for (int off = 1; off < 256; off <<= 1){
        int x = (t >= off) ? ts[t - off] : 0;
        __syncthreads();
        ts[t] += x;
        __syncthreads();
    }
    int run = boff[b] + ts[t] - s;      // exclusive prefix
#pragma unroll
    for (int k = 0; k < 4; k++){
        int i = base + k;
        if (i < n){ rowptr[i] = run; cursor[i] = run; }
        run += v[k];
    }
}

__global__ void fill_kernel(const void* __restrict__ ei, const int* __restrict__ flags,
                            int* __restrict__ cursor, int* __restrict__ csr_src,
                            int E, int Et){
    int e = blockIdx.x * 256 + threadIdx.x;
    if (e >= Et) return;
    int s, d;
    if (e >= E){ s = e - E; d = s; }
    else if (flags[0]){
        const long long* p = (const long long*)ei;
        s = (int)p[e]; d = (int)p[(size_t)E + e];
    } else {
        const int* p = (const int*)ei;
        s = p[e]; d = p[(size_t)E + e];
    }
    int pos = atomicAdd(&cursor[d], 1);
    csr_src[pos] = s;
}

// ---------------------------------------------------------------- GEMM1 (MFMA) + attn1 fused
// h1b[N,128](bf16) = x @ W1 via 16x16x32 bf16 MFMA. Block tile 64 rows x 128 cols,
// 4 waves x 16 rows. W staged transposed (wls[col][k]) so B-frags are contiguous
// ds_read_b128. Logits as1/ad1 from fp32 accumulators (16-lane shfl reduction);
// head == col-tile index since C1=16.
__global__ __launch_bounds__(256) void gemm1_kernel(const void* __restrict__ xv,
                                                    const float* __restrict__ Wf,
                                                    const float* __restrict__ aS,
                                                    const float* __restrict__ aD,
                                                    const int* __restrict__ flags,
                                                    __hip_bfloat16* __restrict__ h1b,
                                                    float* __restrict__ as1,
                                                    float* __restrict__ ad1, int n){
    __shared__ __align__(16) __bf16 xls[64 * XS];   // 17408 B
    __shared__ __align__(16) __bf16 wls[128 * XS];  // 34816 B  (total ~52 KB -> 3 blocks/CU)
    const int t = threadIdx.x;
    const int row0 = blockIdx.x * 64;

    // stage W transposed: wls[col][k] = W[k][col], fp32 -> bf16
    for (int i = t; i < 128 * 128; i += 256){
        int k = i >> 7, c = i & 127;
        wls[c * XS + k] = (__bf16)Wf[i];
    }
    // stage x rows (bf16), zero-pad tail rows
    {
        const int limit = (n - row0) * 128;
        if (flags[1]){
            const float* xp = (const float*)xv + (size_t)row0 * 128;
            for (int i = t; i < 64 * 128; i += 256){
                float v = (i < limit) ? xp[i] : 0.f;
                xls[(i >> 7) * XS + (i & 127)] = (__bf16)v;
            }
        } else {
            const unsigned short* xp = (const unsigned short*)xv + (size_t)row0 * 128;
            for (int i = t; i < 64 * 128; i += 256){
                unsigned short v = (i < limit) ? xp[i] : (unsigned short)0;
                ((unsigned short*)xls)[(i >> 7) * XS + (i & 127)] = v;
            }
        }
    }
    __syncthreads();

    const int w    = t >> 6;
    const int lane = t & 63;
    const int l15  = lane & 15;
    const int quad = lane >> 4;

    f32x4 acc[8] = {};
    const __bf16* xbase = &xls[(w * 16 + l15) * XS + quad * 8];
    const __bf16* wbase = &wls[l15 * XS + quad * 8];

#pragma unroll
    for (int ks = 0; ks < 4; ks++){
        bf16x8 af = *(const bf16x8*)(xbase + ks * 32);
#pragma unroll
        for (int tt = 0; tt < 8; tt++){
            bf16x8 bfr = *(const bf16x8*)(wbase + tt * 16 * XS + ks * 32);
            acc[tt] = __builtin_amdgcn_mfma_f32_16x16x32_bf16(af, bfr, acc[tt], 0, 0, 0);
        }
    }

    // epilogue: bf16 store + exact fp32 logits (head = tile index tt)
#pragma unroll
    for (int tt = 0; tt < 8; tt++){
        int col = tt * 16 + l15;
        float asv = aS[col], adv = aD[col];
#pragma unroll
        for (int r = 0; r < 4; r++){
            int row = row0 + w * 16 + quad * 4 + r;
            float v = acc[tt][r];
            if (row < n) h1b[(size_t)row * 128 + col] = __float2bfloat16(v);
            float vs = v * asv, vd = v * adv;
#pragma unroll
            for (int off = 1; off < 16; off <<= 1){
                vs += __shfl_xor(vs, off);
                vd += __shfl_xor(vd, off);
            }
            if (l15 == 0 && row < n){
                as1[(size_t)row * 8 + tt] = vs;
                ad1[(size_t)row * 8 + tt] = vd;
            }
        }
    }
}

// ---------------------------------------------------------------- gather L1 (+bias+ELU)
// One wave per dst node. Lane covers channels 2*lane, 2*lane+1 (bf16 pair); head = lane/8.
__global__ __launch_bounds__(256) void gather1_kernel(const int* __restrict__ rowptr,
                                                      const int* __restrict__ csr_src,
                                                      const float* __restrict__ as1,
                                                      const float* __restrict__ ad1,
                                                      const unsigned* __restrict__ h1u,
                                                      const float* __restrict__ b1,
                                                      float* __restrict__ out1, int n){
    int wid = blockIdx.x * 4 + (threadIdx.x >> 6);
    if (wid >= n) return;
    int lane = threadIdx.x & 63;
    int ch0  = lane * 2;
    int h    = lane >> 3;
    int start = rowptr[wid], end = rowptr[wid + 1];
    float adv = ad1[(size_t)wid * 8 + h];
    float den = 0.f, num0 = 0.f, num1 = 0.f;
    int src_next = (start < end) ? csr_src[start] : 0;
    for (int j = start; j < end; j++){
        int src = src_next;
        if (j + 1 < end) src_next = csr_src[j + 1];
        float u = lrelu(as1[(size_t)src * 8 + h] + adv);
        float w = __expf(u);
        unsigned hv = h1u[(size_t)src * 64 + lane];
        den += w;
        num0 += w * lo_bf(hv);
        num1 += w * hi_bf(hv);
    }
    float inv = 1.f / (den + 1e-16f);
    float r0 = num0 * inv + b1[ch0];
    float r1 = num1 * inv + b1[ch0 + 1];
    r0 = r0 > 0.f ? r0 : expm1f(r0);
    r1 = r1 > 0.f ? r1 : expm1f(r1);
    *(float2*)(out1 + (size_t)wid * 128 + ch0) = make_float2(r0, r1);
}

// ---------------------------------------------------------------- GEMM2 + attn2 fused
// h2b[N,32](bf16) = out1 @ W2; as2/ad2[N] from fp32 accumulators.
__global__ __launch_bounds__(256) void gemm2_kernel(const float* __restrict__ act,
                                                    const float* __restrict__ W2,
                                                    const float* __restrict__ aS,
                                                    const float* __restrict__ aD,
                                                    __hip_bfloat16* __restrict__ h2b,
                                                    float* __restrict__ as2,
                                                    float* __restrict__ ad2, int n){
    __shared__ float ws[128 * 32];                 // 16 KB
    const int t = threadIdx.x;
    for (int i = t; i < 128*32; i += 256) ws[i] = W2[i];
    __syncthreads();
    int row = blockIdx.x * 8 + (t >> 5);
    int col = t & 31;
    int lane = t & 63;
    if (row >= n) return;
    const float* ar = act + (size_t)row * 128;
    float acc = 0.f;
    for (int k = 0; k < 128; k++) acc += ar[k] * ws[k*32 + col];
    h2b[(size_t)row*32 + col] = __float2bfloat16(acc);
    float vs = acc * aS[col];
    float vd = acc * aD[col];
#pragma unroll
    for (int off = 1; off < 32; off <<= 1){
        vs += __shfl_xor(vs, off);
        vd += __shfl_xor(vd, off);
    }
    if ((lane & 31) == 0){
        as2[row] = vs;
        ad2[row] = vd;
    }
}

// ---------------------------------------------------------------- gather L2 + head (fused)
// One wave per dst node, 4 edges in flight (16 lanes each, 2 bf16 ch/lane).
__global__ __launch_bounds__(256) void gather2_kernel(const int* __restrict__ rowptr,
                                                      const int* __restrict__ csr_src,
                                                      const float* __restrict__ as2,
                                                      const float* __restrict__ ad2,
                                                      const unsigned* __restrict__ h2u,
                                                      const float* __restrict__ b2,
                                                      const float* __restrict__ Wh,
                                                      const float* __restrict__ bh,
                                                      const int* __restrict__ flags,
                                                      void* __restrict__ out, int n){
    int wid = blockIdx.x * 4 + (threadIdx.x >> 6);
    if (wid >= n) return;
    int lane = threadIdx.x & 63;
    int q    = lane >> 4;                           // which of 4 concurrent edges
    int i2   = lane & 15;                           // ch pair index
    int ch0  = i2 * 2;
    int start = rowptr[wid], end = rowptr[wid + 1];
    float adv = ad2[wid];
    float den = 0.f, num0 = 0.f, num1 = 0.f;
    for (int j = start + q; j < end; j += 4){
        int src = csr_src[j];
        float u = lrelu(as2[src] + adv);
        float w = __expf(u);
        unsigned hv = h2u[(size_t)src * 16 + i2];
        den += w;
        num0 += w * lo_bf(hv);
        num1 += w * hi_bf(hv);
    }
    den  += __shfl_xor(den, 16);  den  += __shfl_xor(den, 32);
    num0 += __shfl_xor(num0, 16); num0 += __shfl_xor(num0, 32);
    num1 += __shfl_xor(num1, 16); num1 += __shfl_xor(num1, 32);
    float inv = 1.f / (den + 1e-16f);
    float v0 = num0 * inv + b2[ch0];
    float v1 = num1 * inv + b2[ch0 + 1];
    v0 = v0 > 0.f ? v0 : expm1f(v0);
    v1 = v1 > 0.f ? v1 : expm1f(v1);
    float p = v0 * Wh[ch0] + v1 * Wh[ch0 + 1];
#pragma unroll
    for (int off = 1; off < 16; off <<= 1) p += __shfl_xor(p, off);
    if (lane == 0){
        float r = p + bh[0];
        if (flags[1]) ((float*)out)[wid] = r;
        else          ((__hip_bfloat16*)out)[wid] = __float2bfloat16(r);
    }
}

extern "C" void kernel_launch(void* const* d_in, const int* in_sizes, int n_in,
                              void* d_out, int out_size, void* d_ws, size_t ws_size,
                              hipStream_t stream){
    const void* x   = d_in[0];
    const void* ei  = d_in[1];

    const int Nn = in_sizes[0] / 128;     // 100000
    const int Ee = in_sizes[1] / 2;       // 1600000
    const int Et = Ee + Nn;               // 1700000
    const int nb = (Nn + CHUNK - 1) / CHUNK;

    char* ws = (char*)d_ws;
    auto al = [](size_t v){ return (v + 255) & ~(size_t)255; };
    size_t off = 0;
    int*   flags  = (int*)(ws + off);   off = al(off + 16);
    float* wts    = (float*)(ws + off); off = al(off + (size_t)WTS_TOTAL * 4);
    int*   deg    = (int*)(ws + off);   off = al(off + (size_t)Nn * 4);
    int*   bsum   = (int*)(ws + off);   off = al(off + (size_t)nb * 4);
    int*   boff   = (int*)(ws + off);   off = al(off + (size_t)nb * 4);
    int*   rowptr = (int*)(ws + off);   off = al(off + (size_t)(Nn + 1) * 4);
    int*   cursor = (int*)(ws + off);   off = al(off + (size_t)Nn * 4);
    int*   csrs   = (int*)(ws + off);   off = al(off + (size_t)Et * 4);
    size_t o_h1 = off;
    __hip_bfloat16* h1b = (__hip_bfloat16*)(ws + off); off = al(off + (size_t)Nn * 128 * 2);
    float* as1  = (float*)(ws + off); off = al(off + (size_t)Nn * 8 * 4);
    float* ad1  = (float*)(ws + off); off = al(off + (size_t)Nn * 8 * 4);
    float* out1 = (float*)(ws + off); off = al(off + (size_t)Nn * 128 * 4);
    // layer-2 buffers alias h1b region (dead after gather1)
    size_t o2 = o_h1;
    __hip_bfloat16* h2b = (__hip_bfloat16*)(ws + o2); o2 += (size_t)Nn * 32 * 2;
    float* as2  = (float*)(ws + o2);  o2 += (size_t)Nn * 4;
    float* ad2  = (float*)(ws + o2);  o2 += (size_t)Nn * 4;

    float* W1f  = wts;
    float* W2f  = wts + 16384;
    float* a1sf = wts + 20480;
    float* a1df = wts + 20608;
    float* b1f  = wts + 20736;
    float* a2sf = wts + 20864;
    float* a2df = wts + 20896;
    float* b2f  = wts + 20928;
    float* Whf  = wts + 20960;
    float* bhf  = wts + 20992;

    // detection + weight prep
    detect_kernel<<<1, 64, 0, stream>>>((const unsigned*)ei, (const unsigned*)x, flags);
    prep_w_kernel<<<(WTS_TOTAL + 255) / 256, 256, 0, stream>>>(d_in[2], d_in[6], d_in[3],
        d_in[4], d_in[5], d_in[7], d_in[8], d_in[9], d_in[10], d_in[11], flags, wts);

    // CSR build (dst-bucketed, shared by both layers)
    hipMemsetAsync(deg, 0, (size_t)Nn * 4, stream);
    deg_kernel<<<(Et + 255) / 256, 256, 0, stream>>>(ei, flags, deg, Ee, Et);
    scanA_kernel<<<nb, 256, 0, stream>>>(deg, bsum, Nn);
    scanB_kernel<<<1, 64, 0, stream>>>(bsum, boff, rowptr, nb, Nn);
    scanC_kernel<<<nb, 256, 0, stream>>>(deg, boff, rowptr, cursor, Nn);
    fill_kernel<<<(Et + 255) / 256, 256, 0, stream>>>(ei, flags, cursor, csrs, Ee, Et);

    // layer 1
    gemm1_kernel<<<(Nn + 63) / 64, 256, 0, stream>>>(x, W1f, a1sf, a1df, flags,
                                                     h1b, as1, ad1, Nn);
    gather1_kernel<<<(Nn + 3) / 4, 256, 0, stream>>>(rowptr, csrs, as1, ad1,
                                                     (const unsigned*)h1b, b1f, out1, Nn);

    // layer 2
    gemm2_kernel<<<(Nn + 7) / 8, 256, 0, stream>>>(out1, W2f, a2sf, a2df, h2b, as2, ad2, Nn);
    gather2_kernel<<<(Nn + 3) / 4, 256, 0, stream>>>(rowptr, csrs, as2, ad2,
                                                     (const unsigned*)h2b, b2f,
                                                     Whf, bhf, flags, d_out, Nn);
}

// Round 6
// 475.661 us; speedup vs baseline: 9.7811x; 1.3352x over previous
//
#include <hip/hip_runtime.h>
#include <hip/hip_bf16.h>
#include <stdint.h>
#include <stddef.h>

#define NEG_SLOPE 0.2f
#define XS 136   // padded LDS row stride in bf16 elems (272 B, 16B-aligned, kills 256B bank alias)

// CSR bucket build: bucket = dst >> 9 (512 nodes/bucket), 196 buckets for N=100k.
// BCAP must exceed max bucket population (mean 8704, sigma ~93 for uniform dst).
#define NBK   196
#define BWSH  9
#define BCAP  12288

typedef __bf16 bf16x8 __attribute__((ext_vector_type(8)));
typedef float  f32x4  __attribute__((ext_vector_type(4)));

__device__ __forceinline__ float bf2f(__hip_bfloat16 b){ return __bfloat162float(b); }
__device__ __forceinline__ float lo_bf(unsigned u){ return __uint_as_float(u << 16); }
__device__ __forceinline__ float hi_bf(unsigned u){ return __uint_as_float(u & 0xffff0000u); }
__device__ __forceinline__ float lrelu(float u){ return fmaxf(u, NEG_SLOPE * u); }

// ---------------------------------------------------------------- detect + gcur init
// flags[0]: 1 if edge_index is int64, 0 if int32.
// flags[1]: 1 if float tensors are fp32, 0 if bf16.
__global__ void detect_kernel(const unsigned* __restrict__ ei,
                              const unsigned* __restrict__ xw,
                              int* __restrict__ flags,
                              int* __restrict__ gcur){
    int t = threadIdx.x;
    if (t < NBK) gcur[t] = t * BCAP;            // init bucket cursors
    if (t == 0){
        int is64 = 1;
        for (int i = 0; i < 64; i++)
            if (ei[2*i + 1] != 0u){ is64 = 0; break; }
        flags[0] = is64;
        int plaus = 0;
        for (int i = 0; i < 256; i++){
            unsigned lo = xw[i] & 0xffffu;
            unsigned e  = (lo >> 7) & 0xffu;
            if ((lo & 0x7fffu) == 0u || (e >= 100u && e <= 140u)) plaus++;
        }
        flags[1] = (plaus < 128) ? 1 : 0;
    }
}

// ---------------------------------------------------------------- weights -> fp32
#define WTS_TOTAL 20993
__global__ void prep_w_kernel(const void* W1, const void* W2, const void* a1s,
                              const void* a1d, const void* b1, const void* a2s,
                              const void* a2d, const void* b2, const void* Wh,
                              const void* bh, const int* __restrict__ flags,
                              float* __restrict__ w){
    int i = blockIdx.x * 256 + threadIdx.x;
    if (i >= WTS_TOTAL) return;
    const void* src; int off;
    if      (i < 16384){ src = W1;  off = i; }
    else if (i < 20480){ src = W2;  off = i - 16384; }
    else if (i < 20608){ src = a1s; off = i - 20480; }
    else if (i < 20736){ src = a1d; off = i - 20608; }
    else if (i < 20864){ src = b1;  off = i - 20736; }
    else if (i < 20896){ src = a2s; off = i - 20864; }
    else if (i < 20928){ src = a2d; off = i - 20896; }
    else if (i < 20960){ src = b2;  off = i - 20928; }
    else if (i < 20992){ src = Wh;  off = i - 20960; }
    else               { src = bh;  off = 0; }
    w[i] = flags[1] ? ((const float*)src)[off]
                    : bf2f(((const __hip_bfloat16*)src)[off]);
}

// ---------------------------------------------------------------- phase 1: bucket scatter
// Tile of 4096 edges staged in LDS; per-tile bucket histogram; ONE global atomic
// per (block,bucket) to reserve space; ranked scatter of (src,dst) pairs.
__global__ __launch_bounds__(256) void bucket_scatter_kernel(const void* __restrict__ ei,
                                                             const int* __restrict__ flags,
                                                             int* __restrict__ gcur,
                                                             int2* __restrict__ pairs,
                                                             int E, int Et){
    __shared__ int2 tile[4096];                 // 32 KB
    __shared__ int cnt[NBK], base[NBK], lcnt[NBK];
    const int t = threadIdx.x;
    const int e0 = blockIdx.x * 4096;
    const int nE = min(4096, Et - e0);
    for (int i = t; i < NBK; i += 256){ cnt[i] = 0; lcnt[i] = 0; }
    __syncthreads();
    const int is64 = flags[0];
    for (int j = t; j < nE; j += 256){
        int e = e0 + j;
        int s, d;
        if (e >= E){ s = e - E; d = s; }
        else if (is64){
            const long long* p = (const long long*)ei;
            s = (int)p[e]; d = (int)p[(size_t)E + e];
        } else {
            const int* p = (const int*)ei;
            s = p[e]; d = p[(size_t)E + e];
        }
        tile[j] = make_int2(s, d);
        atomicAdd(&cnt[d >> BWSH], 1);
    }
    __syncthreads();
    for (int b = t; b < NBK; b += 256)
        base[b] = cnt[b] ? atomicAdd(&gcur[b], cnt[b]) : 0;
    __syncthreads();
    for (int j = t; j < nE; j += 256){
        int2 sd = tile[j];
        int b = sd.y >> BWSH;
        int r = atomicAdd(&lcnt[b], 1);
        pairs[(size_t)base[b] + r] = sd;
    }
}

// ---------------------------------------------------------------- phase 1b: bucket base scan
__global__ void bucket_scan_kernel(const int* __restrict__ gcur, int* __restrict__ bbase,
                                   int* __restrict__ rowptr, int Nn){
    __shared__ int sh[256];
    int t = threadIdx.x;
    int s = (t < NBK) ? (gcur[t] - t * BCAP) : 0;
    sh[t] = s; __syncthreads();
    for (int off = 1; off < 256; off <<= 1){
        int v = (t >= off) ? sh[t - off] : 0;
        __syncthreads();
        sh[t] += v;
        __syncthreads();
    }
    int incl = sh[t];
    if (t < NBK) bbase[t] = incl - s;            // exclusive
    if (t == NBK - 1){ bbase[NBK] = incl; rowptr[Nn] = incl; }
}

// ---------------------------------------------------------------- phase 2: per-bucket CSR
// One block per bucket: per-node histogram + scan in LDS -> rowptr; LDS-cursor
// scatter of csr_src into the bucket's contiguous region (XCD-local writes).
__global__ __launch_bounds__(256) void csr_build_kernel(const int2* __restrict__ pairs,
                                                        const int* __restrict__ gcur,
                                                        const int* __restrict__ bbase,
                                                        int* __restrict__ rowptr,
                                                        int* __restrict__ csr_src, int Nn){
    __shared__ int cnt[512];
    __shared__ int sh[256];
    const int b = blockIdx.x, t = threadIdx.x;
    const int sz = gcur[b] - b * BCAP;
    const int eb = bbase[b];
    const int2* pp = pairs + (size_t)b * BCAP;
    cnt[t] = 0; cnt[t + 256] = 0;
    __syncthreads();
    for (int i = t; i < sz; i += 256) atomicAdd(&cnt[pp[i].y & 511], 1);
    __syncthreads();
    int l0 = 2*t, l1 = 2*t + 1;
    int s0 = cnt[l0], s1 = cnt[l1], ts = s0 + s1;
    sh[t] = ts; __syncthreads();
    for (int off = 1; off < 256; off <<= 1){
        int v = (t >= off) ? sh[t - off] : 0;
        __syncthreads();
        sh[t] += v;
        __syncthreads();
    }
    int excl = sh[t] - ts;
    __syncthreads();                              // all cnt reads done
    cnt[l0] = eb + excl;                          // cursor init (reuse cnt)
    cnt[l1] = eb + excl + s0;
    int n0 = (b << BWSH) + l0, n1 = (b << BWSH) + l1;
    if (n0 < Nn) rowptr[n0] = cnt[l0];
    if (n1 < Nn) rowptr[n1] = cnt[l1];
    __syncthreads();
    for (int i = t; i < sz; i += 256){
        int2 sd = pp[i];
        int pos = atomicAdd(&cnt[sd.y & 511], 1);
        csr_src[pos] = sd.x;
    }
}

// ---------------------------------------------------------------- GEMM1 (MFMA) + attn1 fused
__global__ __launch_bounds__(256) void gemm1_kernel(const void* __restrict__ xv,
                                                    const float* __restrict__ Wf,
                                                    const float* __restrict__ aS,
                                                    const float* __restrict__ aD,
                                                    const int* __restrict__ flags,
                                                    __hip_bfloat16* __restrict__ h1b,
                                                    float* __restrict__ as1,
                                                    float* __restrict__ ad1, int n){
    __shared__ __align__(16) __bf16 xls[64 * XS];   // 17408 B
    __shared__ __align__(16) __bf16 wls[128 * XS];  // 34816 B
    const int t = threadIdx.x;
    const int row0 = blockIdx.x * 64;

    for (int i = t; i < 128 * 128; i += 256){
        int k = i >> 7, c = i & 127;
        wls[c * XS + k] = (__bf16)Wf[i];
    }
    {
        const int limit = (n - row0) * 128;
        if (flags[1]){
            const float* xp = (const float*)xv + (size_t)row0 * 128;
            for (int i = t; i < 64 * 128; i += 256){
                float v = (i < limit) ? xp[i] : 0.f;
                xls[(i >> 7) * XS + (i & 127)] = (__bf16)v;
            }
        } else {
            const unsigned short* xp = (const unsigned short*)xv + (size_t)row0 * 128;
            for (int i = t; i < 64 * 128; i += 256){
                unsigned short v = (i < limit) ? xp[i] : (unsigned short)0;
                ((unsigned short*)xls)[(i >> 7) * XS + (i & 127)] = v;
            }
        }
    }
    __syncthreads();

    const int w    = t >> 6;
    const int lane = t & 63;
    const int l15  = lane & 15;
    const int quad = lane >> 4;

    f32x4 acc[8] = {};
    const __bf16* xbase = &xls[(w * 16 + l15) * XS + quad * 8];
    const __bf16* wbase = &wls[l15 * XS + quad * 8];

#pragma unroll
    for (int ks = 0; ks < 4; ks++){
        bf16x8 af = *(const bf16x8*)(xbase + ks * 32);
#pragma unroll
        for (int tt = 0; tt < 8; tt++){
            bf16x8 bfr = *(const bf16x8*)(wbase + tt * 16 * XS + ks * 32);
            acc[tt] = __builtin_amdgcn_mfma_f32_16x16x32_bf16(af, bfr, acc[tt], 0, 0, 0);
        }
    }

#pragma unroll
    for (int tt = 0; tt < 8; tt++){
        int col = tt * 16 + l15;
        float asv = aS[col], adv = aD[col];
#pragma unroll
        for (int r = 0; r < 4; r++){
            int row = row0 + w * 16 + quad * 4 + r;
            float v = acc[tt][r];
            if (row < n) h1b[(size_t)row * 128 + col] = __float2bfloat16(v);
            float vs = v * asv, vd = v * adv;
#pragma unroll
            for (int off = 1; off < 16; off <<= 1){
                vs += __shfl_xor(vs, off);
                vd += __shfl_xor(vd, off);
            }
            if (l15 == 0 && row < n){
                as1[(size_t)row * 8 + tt] = vs;
                ad1[(size_t)row * 8 + tt] = vd;
            }
        }
    }
}

// ---------------------------------------------------------------- gather L1 (+bias+ELU)
__global__ __launch_bounds__(256) void gather1_kernel(const int* __restrict__ rowptr,
                                                      const int* __restrict__ csr_src,
                                                      const float* __restrict__ as1,
                                                      const float* __restrict__ ad1,
                                                      const unsigned* __restrict__ h1u,
                                                      const float* __restrict__ b1,
                                                      float* __restrict__ out1, int n){
    int wid = blockIdx.x * 4 + (threadIdx.x >> 6);
    if (wid >= n) return;
    int lane = threadIdx.x & 63;
    int ch0  = lane * 2;
    int h    = lane >> 3;
    int start = rowptr[wid], end = rowptr[wid + 1];
    float adv = ad1[(size_t)wid * 8 + h];
    float den = 0.f, num0 = 0.f, num1 = 0.f;
    int src_next = (start < end) ? csr_src[start] : 0;
    for (int j = start; j < end; j++){
        int src = src_next;
        if (j + 1 < end) src_next = csr_src[j + 1];
        float u = lrelu(as1[(size_t)src * 8 + h] + adv);
        float w = __expf(u);
        unsigned hv = h1u[(size_t)src * 64 + lane];
        den += w;
        num0 += w * lo_bf(hv);
        num1 += w * hi_bf(hv);
    }
    float inv = 1.f / (den + 1e-16f);
    float r0 = num0 * inv + b1[ch0];
    float r1 = num1 * inv + b1[ch0 + 1];
    r0 = r0 > 0.f ? r0 : expm1f(r0);
    r1 = r1 > 0.f ? r1 : expm1f(r1);
    *(float2*)(out1 + (size_t)wid * 128 + ch0) = make_float2(r0, r1);
}

// ---------------------------------------------------------------- GEMM2 + attn2 fused
__global__ __launch_bounds__(256) void gemm2_kernel(const float* __restrict__ act,
                                                    const float* __restrict__ W2,
                                                    const float* __restrict__ aS,
                                                    const float* __restrict__ aD,
                                                    __hip_bfloat16* __restrict__ h2b,
                                                    float* __restrict__ as2,
                                                    float* __restrict__ ad2, int n){
    __shared__ float ws[128 * 32];                 // 16 KB
    const int t = threadIdx.x;
    for (int i = t; i < 128*32; i += 256) ws[i] = W2[i];
    __syncthreads();
    int row = blockIdx.x * 8 + (t >> 5);
    int col = t & 31;
    int lane = t & 63;
    if (row >= n) return;
    const float* ar = act + (size_t)row * 128;
    float acc = 0.f;
    for (int k = 0; k < 128; k++) acc += ar[k] * ws[k*32 + col];
    h2b[(size_t)row*32 + col] = __float2bfloat16(acc);
    float vs = acc * aS[col];
    float vd = acc * aD[col];
#pragma unroll
    for (int off = 1; off < 32; off <<= 1){
        vs += __shfl_xor(vs, off);
        vd += __shfl_xor(vd, off);
    }
    if ((lane & 31) == 0){
        as2[row] = vs;
        ad2[row] = vd;
    }
}

// ---------------------------------------------------------------- gather L2 + head (fused)
__global__ __launch_bounds__(256) void gather2_kernel(const int* __restrict__ rowptr,
                                                      const int* __restrict__ csr_src,
                                                      const float* __restrict__ as2,
                                                      const float* __restrict__ ad2,
                                                      const unsigned* __restrict__ h2u,
                                                      const float* __restrict__ b2,
                                                      const float* __restrict__ Wh,
                                                      const float* __restrict__ bh,
                                                      const int* __restrict__ flags,
                                                      void* __restrict__ out, int n){
    int wid = blockIdx.x * 4 + (threadIdx.x >> 6);
    if (wid >= n) return;
    int lane = threadIdx.x & 63;
    int q    = lane >> 4;
    int i2   = lane & 15;
    int ch0  = i2 * 2;
    int start = rowptr[wid], end = rowptr[wid + 1];
    float adv = ad2[wid];
    float den = 0.f, num0 = 0.f, num1 = 0.f;
    for (int j = start + q; j < end; j += 4){
        int src = csr_src[j];
        float u = lrelu(as2[src] + adv);
        float w = __expf(u);
        unsigned hv = h2u[(size_t)src * 16 + i2];
        den += w;
        num0 += w * lo_bf(hv);
        num1 += w * hi_bf(hv);
    }
    den  += __shfl_xor(den, 16);  den  += __shfl_xor(den, 32);
    num0 += __shfl_xor(num0, 16); num0 += __shfl_xor(num0, 32);
    num1 += __shfl_xor(num1, 16); num1 += __shfl_xor(num1, 32);
    float inv = 1.f / (den + 1e-16f);
    float v0 = num0 * inv + b2[ch0];
    float v1 = num1 * inv + b2[ch0 + 1];
    v0 = v0 > 0.f ? v0 : expm1f(v0);
    v1 = v1 > 0.f ? v1 : expm1f(v1);
    float p = v0 * Wh[ch0] + v1 * Wh[ch0 + 1];
#pragma unroll
    for (int off = 1; off < 16; off <<= 1) p += __shfl_xor(p, off);
    if (lane == 0){
        float r = p + bh[0];
        if (flags[1]) ((float*)out)[wid] = r;
        else          ((__hip_bfloat16*)out)[wid] = __float2bfloat16(r);
    }
}

extern "C" void kernel_launch(void* const* d_in, const int* in_sizes, int n_in,
                              void* d_out, int out_size, void* d_ws, size_t ws_size,
                              hipStream_t stream){
    const void* x   = d_in[0];
    const void* ei  = d_in[1];

    const int Nn = in_sizes[0] / 128;     // 100000
    const int Ee = in_sizes[1] / 2;       // 1600000
    const int Et = Ee + Nn;               // 1700000

    char* ws = (char*)d_ws;
    auto al = [](size_t v){ return (v + 255) & ~(size_t)255; };
    size_t off = 0;
    int*   flags  = (int*)(ws + off);   off = al(off + 16);
    float* wts    = (float*)(ws + off); off = al(off + (size_t)WTS_TOTAL * 4);
    int*   gcur   = (int*)(ws + off);   off = al(off + (size_t)NBK * 4);
    int*   bbase  = (int*)(ws + off);   off = al(off + (size_t)(NBK + 1) * 4);
    int*   rowptr = (int*)(ws + off);   off = al(off + (size_t)(Nn + 1) * 4);
    int*   csrs   = (int*)(ws + off);   off = al(off + (size_t)Et * 4);
    int2*  pairs  = (int2*)(ws + off);  off = al(off + (size_t)NBK * BCAP * 8);
    size_t o_h1 = off;
    __hip_bfloat16* h1b = (__hip_bfloat16*)(ws + off); off = al(off + (size_t)Nn * 128 * 2);
    float* as1  = (float*)(ws + off); off = al(off + (size_t)Nn * 8 * 4);
    float* ad1  = (float*)(ws + off); off = al(off + (size_t)Nn * 8 * 4);
    float* out1 = (float*)(ws + off); off = al(off + (size_t)Nn * 128 * 4);
    // layer-2 buffers alias h1b region (dead after gather1)
    size_t o2 = o_h1;
    __hip_bfloat16* h2b = (__hip_bfloat16*)(ws + o2); o2 += (size_t)Nn * 32 * 2;
    float* as2  = (float*)(ws + o2);  o2 += (size_t)Nn * 4;
    float* ad2  = (float*)(ws + o2);  o2 += (size_t)Nn * 4;

    float* W1f  = wts;
    float* W2f  = wts + 16384;
    float* a1sf = wts + 20480;
    float* a1df = wts + 20608;
    float* b1f  = wts + 20736;
    float* a2sf = wts + 20864;
    float* a2df = wts + 20896;
    float* b2f  = wts + 20928;
    float* Whf  = wts + 20960;
    float* bhf  = wts + 20992;

    // detection + gcur init + weight prep
    detect_kernel<<<1, 256, 0, stream>>>((const unsigned*)ei, (const unsigned*)x, flags, gcur);
    prep_w_kernel<<<(WTS_TOTAL + 255) / 256, 256, 0, stream>>>(d_in[2], d_in[6], d_in[3],
        d_in[4], d_in[5], d_in[7], d_in[8], d_in[9], d_in[10], d_in[11], flags, wts);

    // CSR build: bucket scatter -> bucket scan -> per-bucket CSR
    bucket_scatter_kernel<<<(Et + 4095) / 4096, 256, 0, stream>>>(ei, flags, gcur, pairs, Ee, Et);
    bucket_scan_kernel<<<1, 256, 0, stream>>>(gcur, bbase, rowptr, Nn);
    csr_build_kernel<<<NBK, 256, 0, stream>>>(pairs, gcur, bbase, rowptr, csrs, Nn);

    // layer 1
    gemm1_kernel<<<(Nn + 63) / 64, 256, 0, stream>>>(x, W1f, a1sf, a1df, flags,
                                                     h1b, as1, ad1, Nn);
    gather1_kernel<<<(Nn + 3) / 4, 256, 0, stream>>>(rowptr, csrs, as1, ad1,
                                                     (const unsigned*)h1b, b1f, out1, Nn);

    // layer 2
    gemm2_kernel<<<(Nn + 7) / 8, 256, 0, stream>>>(out1, W2f, a2sf, a2df, h2b, as2, ad2, Nn);
    gather2_kernel<<<(Nn + 3) / 4, 256, 0, stream>>>(rowptr, csrs, as2, ad2,
                                                     (const unsigned*)h2b, b2f,
                                                     Whf, bhf, flags, d_out, Nn);
}

// Round 7
// 405.077 us; speedup vs baseline: 11.4854x; 1.1742x over previous
//
#include <hip/hip_runtime.h>
#include <hip/hip_bf16.h>
#include <stdint.h>
#include <stddef.h>

#define NEG_SLOPE 0.2f
#define XS 136   // padded LDS row stride in bf16 elems (272 B, 16B-aligned, kills 256B bank alias)

// CSR bucket build: bucket = dst >> 9 (512 nodes/bucket), 196 buckets for N=100k.
#define NBK   196
#define BWSH  9
#define BCAP  12288
// NOTE: packed pair = (src<<9)|(dst&511) requires N < 2^17 (here N=100000). 

typedef __bf16 bf16x8 __attribute__((ext_vector_type(8)));
typedef float  f32x4  __attribute__((ext_vector_type(4)));

__device__ __forceinline__ float bf2f(__hip_bfloat16 b){ return __bfloat162float(b); }
__device__ __forceinline__ float lo_bf(unsigned u){ return __uint_as_float(u << 16); }
__device__ __forceinline__ float hi_bf(unsigned u){ return __uint_as_float(u & 0xffff0000u); }
__device__ __forceinline__ float lrelu(float u){ return fmaxf(u, NEG_SLOPE * u); }
__device__ __forceinline__ unsigned short f2bf(float f){           // RNE bf16
    unsigned u = __float_as_uint(f);
    return (unsigned short)((u + 0x7fffu + ((u >> 16) & 1u)) >> 16);
}

// ---------------------------------------------------------------- detect + gcur init
__global__ void detect_kernel(const unsigned* __restrict__ ei,
                              const unsigned* __restrict__ xw,
                              int* __restrict__ flags,
                              int* __restrict__ gcur){
    int t = threadIdx.x;
    if (t < NBK) gcur[t] = t * BCAP;            // init bucket cursors
    if (t == 0){
        int is64 = 1;
        for (int i = 0; i < 64; i++)
            if (ei[2*i + 1] != 0u){ is64 = 0; break; }
        flags[0] = is64;
        int plaus = 0;
        for (int i = 0; i < 256; i++){
            unsigned lo = xw[i] & 0xffffu;
            unsigned e  = (lo >> 7) & 0xffu;
            if ((lo & 0x7fffu) == 0u || (e >= 100u && e <= 140u)) plaus++;
        }
        flags[1] = (plaus < 128) ? 1 : 0;
    }
}

// ---------------------------------------------------------------- weights -> fp32
#define WTS_TOTAL 20993
__global__ void prep_w_kernel(const void* W1, const void* W2, const void* a1s,
                              const void* a1d, const void* b1, const void* a2s,
                              const void* a2d, const void* b2, const void* Wh,
                              const void* bh, const int* __restrict__ flags,
                              float* __restrict__ w){
    int i = blockIdx.x * 256 + threadIdx.x;
    if (i >= WTS_TOTAL) return;
    const void* src; int off;
    if      (i < 16384){ src = W1;  off = i; }
    else if (i < 20480){ src = W2;  off = i - 16384; }
    else if (i < 20608){ src = a1s; off = i - 20480; }
    else if (i < 20736){ src = a1d; off = i - 20608; }
    else if (i < 20864){ src = b1;  off = i - 20736; }
    else if (i < 20896){ src = a2s; off = i - 20864; }
    else if (i < 20928){ src = a2d; off = i - 20896; }
    else if (i < 20960){ src = b2;  off = i - 20928; }
    else if (i < 20992){ src = Wh;  off = i - 20960; }
    else               { src = bh;  off = 0; }
    w[i] = flags[1] ? ((const float*)src)[off]
                    : bf2f(((const __hip_bfloat16*)src)[off]);
}

// ---------------------------------------------------------------- phase 1: bucket scatter
__global__ __launch_bounds__(256) void bucket_scatter_kernel(const void* __restrict__ ei,
                                                             const int* __restrict__ flags,
                                                             int* __restrict__ gcur,
                                                             unsigned* __restrict__ pairs,
                                                             int E, int Et){
    __shared__ int2 tile[4096];                 // 32 KB
    __shared__ int cnt[NBK], base[NBK], lcnt[NBK];
    const int t = threadIdx.x;
    const int e0 = blockIdx.x * 4096;
    const int nE = min(4096, Et - e0);
    for (int i = t; i < NBK; i += 256){ cnt[i] = 0; lcnt[i] = 0; }
    __syncthreads();
    const int is64 = flags[0];
    for (int j = t; j < nE; j += 256){
        int e = e0 + j;
        int s, d;
        if (e >= E){ s = e - E; d = s; }
        else if (is64){
            const long long* p = (const long long*)ei;
            s = (int)p[e]; d = (int)p[(size_t)E + e];
        } else {
            const int* p = (const int*)ei;
            s = p[e]; d = p[(size_t)E + e];
        }
        tile[j] = make_int2(s, d);
        atomicAdd(&cnt[d >> BWSH], 1);
    }
    __syncthreads();
    for (int b = t; b < NBK; b += 256)
        base[b] = cnt[b] ? atomicAdd(&gcur[b], cnt[b]) : 0;
    __syncthreads();
    for (int j = t; j < nE; j += 256){
        int2 sd = tile[j];
        int b = sd.y >> BWSH;
        int r = atomicAdd(&lcnt[b], 1);
        pairs[(size_t)base[b] + r] = ((unsigned)sd.x << BWSH) | (unsigned)(sd.y & 511);
    }
}

// ---------------------------------------------------------------- phase 1b: bucket base scan
__global__ void bucket_scan_kernel(const int* __restrict__ gcur, int* __restrict__ bbase,
                                   int* __restrict__ rowptr, int Nn){
    __shared__ int sh[256];
    int t = threadIdx.x;
    int s = (t < NBK) ? (gcur[t] - t * BCAP) : 0;
    sh[t] = s; __syncthreads();
    for (int off = 1; off < 256; off <<= 1){
        int v = (t >= off) ? sh[t - off] : 0;
        __syncthreads();
        sh[t] += v;
        __syncthreads();
    }
    int incl = sh[t];
    if (t < NBK) bbase[t] = incl - s;            // exclusive
    if (t == NBK - 1){ bbase[NBK] = incl; rowptr[Nn] = incl; }
}

// ---------------------------------------------------------------- phase 2: per-bucket CSR
__global__ __launch_bounds__(256) void csr_build_kernel(const unsigned* __restrict__ pairs,
                                                        const int* __restrict__ gcur,
                                                        const int* __restrict__ bbase,
                                                        int* __restrict__ rowptr,
                                                        int* __restrict__ csr_src, int Nn){
    __shared__ int cnt[512];
    __shared__ int sh[256];
    const int b = blockIdx.x, t = threadIdx.x;
    const int sz = gcur[b] - b * BCAP;
    const int eb = bbase[b];
    const unsigned* pp = pairs + (size_t)b * BCAP;
    cnt[t] = 0; cnt[t + 256] = 0;
    __syncthreads();
    for (int i = t; i < sz; i += 256) atomicAdd(&cnt[pp[i] & 511u], 1);
    __syncthreads();
    int l0 = 2*t, l1 = 2*t + 1;
    int s0 = cnt[l0], s1 = cnt[l1], ts = s0 + s1;
    sh[t] = ts; __syncthreads();
    for (int off = 1; off < 256; off <<= 1){
        int v = (t >= off) ? sh[t - off] : 0;
        __syncthreads();
        sh[t] += v;
        __syncthreads();
    }
    int excl = sh[t] - ts;
    __syncthreads();
    cnt[l0] = eb + excl;
    cnt[l1] = eb + excl + s0;
    int n0 = (b << BWSH) + l0, n1 = (b << BWSH) + l1;
    if (n0 < Nn) rowptr[n0] = cnt[l0];
    if (n1 < Nn) rowptr[n1] = cnt[l1];
    __syncthreads();
    for (int i = t; i < sz; i += 256){
        unsigned sd = pp[i];
        int pos = atomicAdd(&cnt[sd & 511u], 1);
        csr_src[pos] = (int)(sd >> BWSH);
    }
}

// ---------------------------------------------------------------- GEMM1 (MFMA) + attn1 fused
__global__ __launch_bounds__(256) void gemm1_kernel(const void* __restrict__ xv,
                                                    const float* __restrict__ Wf,
                                                    const float* __restrict__ aS,
                                                    const float* __restrict__ aD,
                                                    const int* __restrict__ flags,
                                                    __hip_bfloat16* __restrict__ h1b,
                                                    float* __restrict__ as1,
                                                    float* __restrict__ ad1, int n){
    __shared__ __align__(16) __bf16 xls[64 * XS];   // 17408 B
    __shared__ __align__(16) __bf16 wls[128 * XS];  // 34816 B
    const int t = threadIdx.x;
    const int row0 = blockIdx.x * 64;

    for (int i = t; i < 128 * 128; i += 256){
        int k = i >> 7, c = i & 127;
        wls[c * XS + k] = (__bf16)Wf[i];
    }
    {
        const int limit = (n - row0) * 128;
        if (flags[1]){
            const float* xp = (const float*)xv + (size_t)row0 * 128;
            for (int i = t; i < 64 * 128; i += 256){
                float v = (i < limit) ? xp[i] : 0.f;
                xls[(i >> 7) * XS + (i & 127)] = (__bf16)v;
            }
        } else {
            const unsigned short* xp = (const unsigned short*)xv + (size_t)row0 * 128;
            for (int i = t; i < 64 * 128; i += 256){
                unsigned short v = (i < limit) ? xp[i] : (unsigned short)0;
                ((unsigned short*)xls)[(i >> 7) * XS + (i & 127)] = v;
            }
        }
    }
    __syncthreads();

    const int w    = t >> 6;
    const int lane = t & 63;
    const int l15  = lane & 15;
    const int quad = lane >> 4;

    f32x4 acc[8] = {};
    const __bf16* xbase = &xls[(w * 16 + l15) * XS + quad * 8];
    const __bf16* wbase = &wls[l15 * XS + quad * 8];

#pragma unroll
    for (int ks = 0; ks < 4; ks++){
        bf16x8 af = *(const bf16x8*)(xbase + ks * 32);
#pragma unroll
        for (int tt = 0; tt < 8; tt++){
            bf16x8 bfr = *(const bf16x8*)(wbase + tt * 16 * XS + ks * 32);
            acc[tt] = __builtin_amdgcn_mfma_f32_16x16x32_bf16(af, bfr, acc[tt], 0, 0, 0);
        }
    }

#pragma unroll
    for (int tt = 0; tt < 8; tt++){
        int col = tt * 16 + l15;
        float asv = aS[col], adv = aD[col];
#pragma unroll
        for (int r = 0; r < 4; r++){
            int row = row0 + w * 16 + quad * 4 + r;
            float v = acc[tt][r];
            if (row < n) h1b[(size_t)row * 128 + col] = __float2bfloat16(v);
            float vs = v * asv, vd = v * adv;
#pragma unroll
            for (int off = 1; off < 16; off <<= 1){
                vs += __shfl_xor(vs, off);
                vd += __shfl_xor(vd, off);
            }
            if (l15 == 0 && row < n){
                as1[(size_t)row * 8 + tt] = vs;
                ad1[(size_t)row * 8 + tt] = vd;
            }
        }
    }
}

// ---------------------------------------------------------------- gather L1 (+bias+ELU)
// One wave per dst node, 4 edges in flight (q = lane>>4), 16 lanes per edge,
// 8 channels per lane via one uint4 (64 B — full coalesced lines).
// head = (lane&15)>>1. Combine streams with shfl_xor(16/32). out1 bf16.
__global__ __launch_bounds__(256) void gather1_kernel(const int* __restrict__ rowptr,
                                                      const int* __restrict__ csr_src,
                                                      const float* __restrict__ as1,
                                                      const float* __restrict__ ad1,
                                                      const unsigned* __restrict__ h1u,
                                                      const float* __restrict__ b1,
                                                      unsigned* __restrict__ out1u, int n){
    int wid = blockIdx.x * 4 + (threadIdx.x >> 6);
    if (wid >= n) return;
    const int lane = threadIdx.x & 63;
    const int q    = lane >> 4;
    const int l15  = lane & 15;
    const int h    = l15 >> 1;
    const int start = rowptr[wid], end = rowptr[wid + 1];
    const float adv = ad1[(size_t)wid * 8 + h];
    float den = 0.f;
    float num[8] = {0.f,0.f,0.f,0.f,0.f,0.f,0.f,0.f};
    for (int j = start + q; j < end; j += 4){
        int src = csr_src[j];
        float u = lrelu(as1[(size_t)src * 8 + h] + adv);
        float w = __expf(u);
        uint4 hv = *(const uint4*)(h1u + (size_t)src * 64 + (l15 << 2));
        den += w;
        num[0] += w * lo_bf(hv.x); num[1] += w * hi_bf(hv.x);
        num[2] += w * lo_bf(hv.y); num[3] += w * hi_bf(hv.y);
        num[4] += w * lo_bf(hv.z); num[5] += w * hi_bf(hv.z);
        num[6] += w * lo_bf(hv.w); num[7] += w * hi_bf(hv.w);
    }
    den += __shfl_xor(den, 16); den += __shfl_xor(den, 32);
#pragma unroll
    for (int k = 0; k < 8; k++){
        num[k] += __shfl_xor(num[k], 16);
        num[k] += __shfl_xor(num[k], 32);
    }
    if (lane < 16){
        const int ch0 = l15 * 8;
        float inv = 1.f / (den + 1e-16f);
        uint4 o;
        unsigned* op = (unsigned*)&o;
#pragma unroll
        for (int k = 0; k < 4; k++){
            float r0 = num[2*k]   * inv + b1[ch0 + 2*k];
            float r1 = num[2*k+1] * inv + b1[ch0 + 2*k + 1];
            r0 = r0 > 0.f ? r0 : expm1f(r0);
            r1 = r1 > 0.f ? r1 : expm1f(r1);
            op[k] = (unsigned)f2bf(r0) | ((unsigned)f2bf(r1) << 16);
        }
        *(uint4*)(out1u + (size_t)wid * 64 + (l15 << 2)) = o;
    }
}

// ---------------------------------------------------------------- GEMM2 (MFMA) + attn2 fused
// h2b[N,32](bf16) = out1(bf16) @ W2; 64-row x 32-col tile, 4 waves, K=128.
__global__ __launch_bounds__(256) void gemm2_kernel(const unsigned* __restrict__ out1u,
                                                    const float* __restrict__ W2f,
                                                    const float* __restrict__ aS,
                                                    const float* __restrict__ aD,
                                                    __hip_bfloat16* __restrict__ h2b,
                                                    float* __restrict__ as2,
                                                    float* __restrict__ ad2, int n){
    __shared__ __align__(16) __bf16 als[64 * XS];   // 17408 B
    __shared__ __align__(16) __bf16 wls[32 * XS];   // 8704 B
    const int t = threadIdx.x;
    const int row0 = blockIdx.x * 64;

    for (int i = t; i < 128 * 32; i += 256){
        int k = i >> 5, c = i & 31;
        wls[c * XS + k] = (__bf16)W2f[i];
    }
    {
        const int limit = (n - row0) * 64;          // uints available
        for (int i = t; i < 64 * 64; i += 256){
            unsigned v = (i < limit) ? out1u[(size_t)row0 * 64 + i] : 0u;
            ((unsigned*)als)[(i >> 6) * 68 + (i & 63)] = v;   // 68 = XS/2 uints
        }
    }
    __syncthreads();

    const int w    = t >> 6;
    const int lane = t & 63;
    const int l15  = lane & 15;
    const int quad = lane >> 4;

    f32x4 acc[2] = {};
    const __bf16* abase = &als[(w * 16 + l15) * XS + quad * 8];
    const __bf16* bbase = &wls[l15 * XS + quad * 8];

#pragma unroll
    for (int ks = 0; ks < 4; ks++){
        bf16x8 af = *(const bf16x8*)(abase + ks * 32);
#pragma unroll
        for (int tt = 0; tt < 2; tt++){
            bf16x8 bfr = *(const bf16x8*)(bbase + tt * 16 * XS + ks * 32);
            acc[tt] = __builtin_amdgcn_mfma_f32_16x16x32_bf16(af, bfr, acc[tt], 0, 0, 0);
        }
    }

#pragma unroll
    for (int r = 0; r < 4; r++){
        int row = row0 + w * 16 + quad * 4 + r;
        float vs = 0.f, vd = 0.f;
#pragma unroll
        for (int tt = 0; tt < 2; tt++){
            int col = tt * 16 + l15;
            float v = acc[tt][r];
            if (row < n) h2b[(size_t)row * 32 + col] = __float2bfloat16(v);
            vs += v * aS[col];
            vd += v * aD[col];
        }
#pragma unroll
        for (int off = 1; off < 16; off <<= 1){
            vs += __shfl_xor(vs, off);
            vd += __shfl_xor(vd, off);
        }
        if (l15 == 0 && row < n){
            as2[row] = vs;
            ad2[row] = vd;
        }
    }
}

// ---------------------------------------------------------------- gather L2 + head (fused)
__global__ __launch_bounds__(256) void gather2_kernel(const int* __restrict__ rowptr,
                                                      const int* __restrict__ csr_src,
                                                      const float* __restrict__ as2,
                                                      const float* __restrict__ ad2,
                                                      const unsigned* __restrict__ h2u,
                                                      const float* __restrict__ b2,
                                                      const float* __restrict__ Wh,
                                                      const float* __restrict__ bh,
                                                      const int* __restrict__ flags,
                                                      void* __restrict__ out, int n){
    int wid = blockIdx.x * 4 + (threadIdx.x >> 6);
    if (wid >= n) return;
    int lane = threadIdx.x & 63;
    int q    = lane >> 4;
    int i2   = lane & 15;
    int ch0  = i2 * 2;
    int start = rowptr[wid], end = rowptr[wid + 1];
    float adv = ad2[wid];
    float den = 0.f, num0 = 0.f, num1 = 0.f;
    for (int j = start + q; j < end; j += 4){
        int src = csr_src[j];
        float u = lrelu(as2[src] + adv);
        float w = __expf(u);
        unsigned hv = h2u[(size_t)src * 16 + i2];
        den += w;
        num0 += w * lo_bf(hv);
        num1 += w * hi_bf(hv);
    }
    den  += __shfl_xor(den, 16);  den  += __shfl_xor(den, 32);
    num0 += __shfl_xor(num0, 16); num0 += __shfl_xor(num0, 32);
    num1 += __shfl_xor(num1, 16); num1 += __shfl_xor(num1, 32);
    float inv = 1.f / (den + 1e-16f);
    float v0 = num0 * inv + b2[ch0];
    float v1 = num1 * inv + b2[ch0 + 1];
    v0 = v0 > 0.f ? v0 : expm1f(v0);
    v1 = v1 > 0.f ? v1 : expm1f(v1);
    float p = v0 * Wh[ch0] + v1 * Wh[ch0 + 1];
#pragma unroll
    for (int off = 1; off < 16; off <<= 1) p += __shfl_xor(p, off);
    if (lane == 0){
        float r = p + bh[0];
        if (flags[1]) ((float*)out)[wid] = r;
        else          ((__hip_bfloat16*)out)[wid] = __float2bfloat16(r);
    }
}

extern "C" void kernel_launch(void* const* d_in, const int* in_sizes, int n_in,
                              void* d_out, int out_size, void* d_ws, size_t ws_size,
                              hipStream_t stream){
    const void* x   = d_in[0];
    const void* ei  = d_in[1];

    const int Nn = in_sizes[0] / 128;     // 100000
    const int Ee = in_sizes[1] / 2;       // 1600000
    const int Et = Ee + Nn;               // 1700000

    char* ws = (char*)d_ws;
    auto al = [](size_t v){ return (v + 255) & ~(size_t)255; };
    size_t off = 0;
    int*      flags  = (int*)(ws + off);      off = al(off + 16);
    float*    wts    = (float*)(ws + off);    off = al(off + (size_t)WTS_TOTAL * 4);
    int*      gcur   = (int*)(ws + off);      off = al(off + (size_t)NBK * 4);
    int*      bbase  = (int*)(ws + off);      off = al(off + (size_t)(NBK + 1) * 4);
    int*      rowptr = (int*)(ws + off);      off = al(off + (size_t)(Nn + 1) * 4);
    int*      csrs   = (int*)(ws + off);      off = al(off + (size_t)Et * 4);
    unsigned* pairs  = (unsigned*)(ws + off); off = al(off + (size_t)NBK * BCAP * 4);
    size_t o_h1 = off;
    __hip_bfloat16* h1b = (__hip_bfloat16*)(ws + off); off = al(off + (size_t)Nn * 128 * 2);
    float* as1  = (float*)(ws + off); off = al(off + (size_t)Nn * 8 * 4);
    float* ad1  = (float*)(ws + off); off = al(off + (size_t)Nn * 8 * 4);
    unsigned* out1u = (unsigned*)(ws + off); off = al(off + (size_t)Nn * 128 * 2);
    // layer-2 buffers alias h1b region (dead after gather1)
    size_t o2 = o_h1;
    __hip_bfloat16* h2b = (__hip_bfloat16*)(ws + o2); o2 += (size_t)Nn * 32 * 2;
    float* as2  = (float*)(ws + o2);  o2 += (size_t)Nn * 4;
    float* ad2  = (float*)(ws + o2);  o2 += (size_t)Nn * 4;

    float* W1f  = wts;
    float* W2f  = wts + 16384;
    float* a1sf = wts + 20480;
    float* a1df = wts + 20608;
    float* b1f  = wts + 20736;
    float* a2sf = wts + 20864;
    float* a2df = wts + 20896;
    float* b2f  = wts + 20928;
    float* Whf  = wts + 20960;
    float* bhf  = wts + 20992;

    // detection + gcur init + weight prep
    detect_kernel<<<1, 256, 0, stream>>>((const unsigned*)ei, (const unsigned*)x, flags, gcur);
    prep_w_kernel<<<(WTS_TOTAL + 255) / 256, 256, 0, stream>>>(d_in[2], d_in[6], d_in[3],
        d_in[4], d_in[5], d_in[7], d_in[8], d_in[9], d_in[10], d_in[11], flags, wts);

    // CSR build: bucket scatter -> bucket scan -> per-bucket CSR
    bucket_scatter_kernel<<<(Et + 4095) / 4096, 256, 0, stream>>>(ei, flags, gcur, pairs, Ee, Et);
    bucket_scan_kernel<<<1, 256, 0, stream>>>(gcur, bbase, rowptr, Nn);
    csr_build_kernel<<<NBK, 256, 0, stream>>>(pairs, gcur, bbase, rowptr, csrs, Nn);

    // layer 1
    gemm1_kernel<<<(Nn + 63) / 64, 256, 0, stream>>>(x, W1f, a1sf, a1df, flags,
                                                     h1b, as1, ad1, Nn);
    gather1_kernel<<<(Nn + 3) / 4, 256, 0, stream>>>(rowptr, csrs, as1, ad1,
                                                     (const unsigned*)h1b, b1f, out1u, Nn);

    // layer 2
    gemm2_kernel<<<(Nn + 63) / 64, 256, 0, stream>>>(out1u, W2f, a2sf, a2df, h2b, as2, ad2, Nn);
    gather2_kernel<<<(Nn + 3) / 4, 256, 0, stream>>>(rowptr, csrs, as2, ad2,
                                                     (const unsigned*)h2b, b2f,
                                                     Whf, bhf, flags, d_out, Nn);
}